// Round 3
// baseline (383.947 us; speedup 1.0000x reference)
//
#include <hip/hip_runtime.h>
#include <hip/hip_fp16.h>

#define BATCH 4
#define CH 256
#define HW 4096
#define K_TOP 115
#define COLS 16
#define CAND 128

typedef __attribute__((ext_vector_type(8))) short short8;
typedef __attribute__((ext_vector_type(4))) float f32x4;

__device__ __forceinline__ unsigned short f32_to_bf16(float f) {
  union { float f; unsigned int u; } v; v.f = f;
  unsigned int r = v.u + 0x7fffu + ((v.u >> 16) & 1u);
  return (unsigned short)(r >> 16);
}

__device__ __forceinline__ unsigned int f16key(unsigned short h) {
  // monotone map: f16 bits -> u16 key, ascending float order == ascending key
  return (h & 0x8000u) ? (unsigned int)((unsigned short)~h)
                       : (unsigned int)(h | 0x8000u);
}

__device__ __forceinline__ unsigned short key2f16(unsigned short k) {
  return (k & 0x8000u) ? (unsigned short)(k ^ 0x8000u)
                       : (unsigned short)(~k);
}

// ---------- kernel 1a: rn[b][p] = 1 / max(||x[b,:,p]||, eps) ----------
__global__ void norms_kernel(const float* __restrict__ x, float* __restrict__ rn) {
  int b = blockIdx.x >> 4;
  int p = ((blockIdx.x & 15) << 8) + threadIdx.x;
  const float* xb = x + (size_t)b * CH * HW + p;
  float ss = 0.f;
  #pragma unroll 8
  for (int c = 0; c < CH; ++c) { float v = xb[(size_t)c * HW]; ss += v * v; }
  rn[b * HW + p] = 1.0f / fmaxf(sqrtf(ss), 1e-12f);
}

// ---------- kernel 1b: xnT[b][p][c] = bf16(x[b][c][p] * rn[b][p]) ----------
__global__ void transpose_kernel(const float* __restrict__ x, const float* __restrict__ rn,
                                 unsigned short* __restrict__ xnT) {
  __shared__ float tile[64][65];
  int blk = blockIdx.x;
  int b = blk >> 8;
  int rem = blk & 255;
  int c0 = (rem >> 6) << 6;
  int p0 = (rem & 63) << 6;
  for (int idx = threadIdx.x; idx < 64 * 64; idx += blockDim.x) {
    int c = idx >> 6, p = idx & 63;
    tile[c][p] = x[((size_t)b * CH + c0 + c) * HW + p0 + p];
  }
  __syncthreads();
  for (int idx = threadIdx.x; idx < 64 * 64; idx += blockDim.x) {
    int p = idx >> 6, c = idx & 63;
    xnT[((size_t)b * HW + p0 + p) * CH + c0 + c] =
        f32_to_bf16(tile[c][p] * rn[b * HW + p0 + p]);
  }
}

// ---------- kernel 2: Gram panel (MFMA, keys in regs) + binary-search top-115 ----------
struct K2Smem {
  unsigned int   swcnt[2][16][COLS];  // per-wave partial counts, double-buffered
  unsigned int   tcol[COLS];          // threshold key per column
  unsigned int   cnt[COLS];
  unsigned short cand[COLS][CAND];
};

// One 16-row i-tile of the Gram panel; T is a compile-time constant so kreg
// indices stay static (runtime-indexed ext-vector arrays go to scratch).
#define GEMM_TILE(T) {                                                         \
    const int i0 = (w + 16 * (T)) * 16;                                        \
    f32x4 acc = {0.f, 0.f, 0.f, 0.f};                                          \
    _Pragma("unroll")                                                          \
    for (int kk = 0; kk < 8; ++kk) {                                           \
      short8 afrag = x8[(i0 + lr) * 32 + kk * 4 + lk];                         \
      acc = __builtin_amdgcn_mfma_f32_16x16x32_bf16(afrag, bfrag[kk], acc,     \
                                                    0, 0, 0);                  \
    }                                                                          \
    kreg[2 * (T)] = f16key(__half_as_ushort(__float2half(acc[0]))) |           \
                    (f16key(__half_as_ushort(__float2half(acc[1]))) << 16);    \
    kreg[2 * (T) + 1] = f16key(__half_as_ushort(__float2half(acc[2]))) |       \
                        (f16key(__half_as_ushort(__float2half(acc[3]))) << 16);\
  }

__launch_bounds__(1024, 4)
__global__ void corr_topk_kernel(const unsigned short* __restrict__ xnT,
                                 float* __restrict__ out) {
  __shared__ K2Smem s;
  const int tid = threadIdx.x;
  const int b  = blockIdx.x >> 8;
  const int j0 = (blockIdx.x & 255) * COLS;
  const short8* x8 = (const short8*)(xnT + (size_t)b * HW * CH);

  const int lane = tid & 63;
  const int w    = tid >> 6;   // 16 waves
  const int lr   = lane & 15;  // fragment row/col index
  const int lk   = lane >> 4;  // k-group

  // B fragments: pixel j0+lr, channels kk*32 + lk*8 .. +8
  short8 bfrag[8];
  #pragma unroll
  for (int kk = 0; kk < 8; ++kk)
    bfrag[kk] = x8[(j0 + lr) * 32 + kk * 4 + lk];

  // ---- GEMM phase: wave w computes i-tiles w, w+16, ...; keys stay in regs.
  // Lane owns column j0+lr; rows i0 + lk*4 + r (C/D layout per m89).
  unsigned int kreg[32];
  GEMM_TILE(0)  GEMM_TILE(1)  GEMM_TILE(2)  GEMM_TILE(3)
  GEMM_TILE(4)  GEMM_TILE(5)  GEMM_TILE(6)  GEMM_TILE(7)
  GEMM_TILE(8)  GEMM_TILE(9)  GEMM_TILE(10) GEMM_TILE(11)
  GEMM_TILE(12) GEMM_TILE(13) GEMM_TILE(14) GEMM_TILE(15)

  // ---- binary search for per-column 115th-largest key ----
  // f(v) = #{key >= v} over the column's 4096 keys (64 owner-threads x 64 each).
  unsigned int lo = 0;
  for (int bit = 15; bit >= 0; --bit) {
    const unsigned int m = lo | (1u << bit);
    int c = 0;
    #pragma unroll
    for (int r = 0; r < 32; ++r) {
      c += ((kreg[r] & 0xffffu) >= m);
      c += ((kreg[r] >> 16) >= m);
    }
    c += __shfl_xor(c, 16);
    c += __shfl_xor(c, 32);
    const int buf = bit & 1;
    if (lane < 16) s.swcnt[buf][w][lane] = (unsigned int)c;
    __syncthreads();
    int tot = 0;
    #pragma unroll
    for (int ww = 0; ww < 16; ++ww) tot += (int)s.swcnt[buf][ww][lr];
    if (tot >= K_TOP) lo = m;
  }
  // lo = max v with f(v) >= 115  => exact threshold key; #{key > lo} <= 114.

  if (w == 0 && lane < 16) { s.tcol[lane] = lo; s.cnt[lane] = 0; }
  __syncthreads();

  // prefill candidate list with the threshold key
  for (int k = tid; k < COLS * CAND; k += 1024)
    s.cand[k >> 7][k & (CAND - 1)] = (unsigned short)s.tcol[k >> 7];
  __syncthreads();

  // scatter strictly-greater keys (<=114 per column -> cheap atomics)
  #pragma unroll
  for (int r = 0; r < 32; ++r) {
    unsigned int p = kreg[r];
    unsigned int a = p & 0xffffu;
    unsigned int bb = p >> 16;
    if (a > lo) {
      unsigned int pos = atomicAdd(&s.cnt[lr], 1u);
      s.cand[lr][pos] = (unsigned short)a;
    }
    if (bb > lo) {
      unsigned int pos = atomicAdd(&s.cnt[lr], 1u);
      s.cand[lr][pos] = (unsigned short)bb;
    }
  }

  // ---- bitonic sort 128 keys per column (64 threads/column), descending ----
  const int col = tid >> 6;
  const int tl  = tid & 63;
  for (int size = 2; size <= CAND; size <<= 1) {
    for (int stride = size >> 1; stride > 0; stride >>= 1) {
      __syncthreads();
      int i = (tl % stride) + 2 * stride * (tl / stride);
      int j = i + stride;
      unsigned short a = s.cand[col][i];
      unsigned short bmm = s.cand[col][j];
      bool desc = ((i & size) == 0);
      if (desc ? (a < bmm) : (a > bmm)) {
        s.cand[col][i] = bmm;
        s.cand[col][j] = a;
      }
    }
  }
  __syncthreads();

  // output: out[b][k][j] = f32(cand[col][k]) / 256
  for (int k = tl; k < K_TOP; k += 64) {
    unsigned short hb = key2f16(s.cand[col][k]);
    float v = __half2float(__ushort_as_half(hb)) * (1.0f / 256.0f);
    out[((size_t)b * K_TOP + k) * HW + j0 + col] = v;
  }
}

extern "C" void kernel_launch(void* const* d_in, const int* in_sizes, int n_in,
                              void* d_out, int out_size, void* d_ws, size_t ws_size,
                              hipStream_t stream) {
  (void)in_sizes; (void)n_in; (void)out_size; (void)ws_size;
  const float* x = (const float*)d_in[0];
  float* out = (float*)d_out;
  float* rn = (float*)d_ws;                                      // 64 KB
  unsigned short* xnT = (unsigned short*)((char*)d_ws + 65536);  // 8 MB bf16

  norms_kernel<<<64, 256, 0, stream>>>(x, rn);
  transpose_kernel<<<1024, 256, 0, stream>>>(x, rn, xnT);
  corr_topk_kernel<<<1024, 1024, 0, stream>>>(xnT, out);
}

// Round 5
// 372.832 us; speedup vs baseline: 1.0298x; 1.0298x over previous
//
#include <hip/hip_runtime.h>
#include <hip/hip_fp16.h>

#define CH 256
#define HW 4096
#define K_TOP 115
#define COLS 16
#define CAND 128
#define CSTRIDE 4104  // u16 per column (4096 + 8 pad); 4104*2 = 8208 B = 16*513 (16B aligned)

typedef __attribute__((ext_vector_type(8))) short short8;
typedef __attribute__((ext_vector_type(4))) float f32x4;
typedef __attribute__((ext_vector_type(4))) unsigned int u32x4;

__device__ __forceinline__ unsigned short f32_to_bf16(float f) {
  union { float f; unsigned int u; } v; v.f = f;
  unsigned int r = v.u + 0x7fffu + ((v.u >> 16) & 1u);
  return (unsigned short)(r >> 16);
}

__device__ __forceinline__ unsigned int f16key(unsigned short h) {
  // monotone map: f16 bits -> u16 key, ascending float order == ascending key
  return (h & 0x8000u) ? (unsigned int)((unsigned short)~h)
                       : (unsigned int)(h | 0x8000u);
}

__device__ __forceinline__ unsigned short key2f16(unsigned int k) {
  return (k & 0x8000u) ? (unsigned short)(k ^ 0x8000u)
                       : (unsigned short)(~k & 0xffffu);
}

__device__ __forceinline__ int cmp2(unsigned int p, unsigned int m) {
  return (int)((p & 0xffffu) >= m) + (int)((p >> 16) >= m);
}

// ---------- kernel 1a: rn[b][p] = 1 / max(||x[b,:,p]||, eps) ----------
__global__ void norms_kernel(const float* __restrict__ x, float* __restrict__ rn) {
  int b = blockIdx.x >> 4;
  int p = ((blockIdx.x & 15) << 8) + threadIdx.x;
  const float* xb = x + (size_t)b * CH * HW + p;
  float ss = 0.f;
  #pragma unroll 8
  for (int c = 0; c < CH; ++c) { float v = xb[(size_t)c * HW]; ss += v * v; }
  rn[b * HW + p] = 1.0f / fmaxf(sqrtf(ss), 1e-12f);
}

// ---------- kernel 1b: xnT[b][p][c] = bf16(x[b][c][p] * rn[b][p]) ----------
__global__ void transpose_kernel(const float* __restrict__ x, const float* __restrict__ rn,
                                 unsigned short* __restrict__ xnT) {
  __shared__ float tile[64][65];
  int blk = blockIdx.x;
  int b = blk >> 8;
  int rem = blk & 255;
  int c0 = (rem >> 6) << 6;
  int p0 = (rem & 63) << 6;
  for (int idx = threadIdx.x; idx < 64 * 64; idx += blockDim.x) {
    int c = idx >> 6, p = idx & 63;
    tile[c][p] = x[((size_t)b * CH + c0 + c) * HW + p0 + p];
  }
  __syncthreads();
  for (int idx = threadIdx.x; idx < 64 * 64; idx += blockDim.x) {
    int p = idx >> 6, c = idx & 63;
    xnT[((size_t)b * HW + p0 + p) * CH + c0 + c] =
        f32_to_bf16(tile[c][p] * rn[b * HW + p0 + p]);
  }
}

// ---------- kernel 2: Gram panel -> LDS keys -> per-wave barrier-free top-115 ----------
struct K2S {
  unsigned short colkeys[COLS][CSTRIDE];  // sortable u16 keys, column-major
  unsigned short cand[COLS][CAND];
  unsigned int   cnt[COLS];
};

__launch_bounds__(1024, 4)
__global__ void corr_topk_kernel(const unsigned short* __restrict__ xnT,
                                 float* __restrict__ out) {
  __shared__ __align__(16) K2S s;
  const int tid  = threadIdx.x;
  const int lane = tid & 63;
  const int w    = tid >> 6;   // 16 waves; wave w also owns column w in selection
  const int lr   = lane & 15;  // MFMA fragment row/col index
  const int lk   = lane >> 4;  // k-group

  // XCD-aware swizzle: blocks with blk&7 == xcd share one batch -> its 2MB
  // A-panel stays resident in that XCD's 4MB L2. Bijective remap.
  const int blk = blockIdx.x;
  const int xcd = blk & 7;
  const int b   = xcd >> 1;
  const int jt  = ((xcd & 1) << 7) + (blk >> 3);
  const int j0  = jt * COLS;
  const short8* x8 = (const short8*)(xnT + (size_t)b * HW * CH);

  // B fragments: pixel j0+lr, channels kk*32 + lk*8 .. +8
  short8 bfrag[8];
  #pragma unroll
  for (int kk = 0; kk < 8; ++kk)
    bfrag[kk] = x8[(j0 + lr) * 32 + kk * 4 + lk];

  // ---- GEMM phase: wave w computes i-tiles w, w+16, ...; keys -> LDS col-major.
  // D layout (m89): lane holds D[row = lk*4 + r][col = lr]; row -> i, col -> j.
  for (int t = 0; t < 16; ++t) {
    const int i0 = (w + 16 * t) * 16;
    f32x4 acc = {0.f, 0.f, 0.f, 0.f};
    #pragma unroll
    for (int kk = 0; kk < 8; ++kk) {
      short8 afrag = x8[(i0 + lr) * 32 + kk * 4 + lk];
      acc = __builtin_amdgcn_mfma_f32_16x16x32_bf16(afrag, bfrag[kk], acc, 0, 0, 0);
    }
    unsigned long long k0 = f16key(__half_as_ushort(__float2half(acc[0])));
    unsigned long long k1 = f16key(__half_as_ushort(__float2half(acc[1])));
    unsigned long long k2 = f16key(__half_as_ushort(__float2half(acc[2])));
    unsigned long long k3 = f16key(__half_as_ushort(__float2half(acc[3])));
    // 8B-aligned: lr*8208 + (i0+lk*4)*2, both multiples of 8
    *(unsigned long long*)&s.colkeys[lr][i0 + lk * 4] =
        k0 | (k1 << 16) | (k2 << 32) | (k3 << 48);
  }
  __syncthreads();  // the ONLY block-wide barrier (also a compiler memory fence)

  // ---- selection: wave w owns column w; everything intra-wave from here ----
  const u32x4* cp = (const u32x4*)&s.colkeys[w][0];
  // contiguous 16B/lane reads: conflict-free
  u32x4 q0 = cp[0 * 64 + lane];
  u32x4 q1 = cp[1 * 64 + lane];
  u32x4 q2 = cp[2 * 64 + lane];
  u32x4 q3 = cp[3 * 64 + lane];
  u32x4 q4 = cp[4 * 64 + lane];
  u32x4 q5 = cp[5 * 64 + lane];
  u32x4 q6 = cp[6 * 64 + lane];
  u32x4 q7 = cp[7 * 64 + lane];

  // binary search: lo = max v with #{key >= v} >= 115 (exact threshold key)
  unsigned int lo = 0;
  #pragma unroll 1
  for (int bit = 15; bit >= 0; --bit) {
    const unsigned int m = lo | (1u << bit);
    int c = 0;
    c += cmp2(q0.x, m) + cmp2(q0.y, m) + cmp2(q0.z, m) + cmp2(q0.w, m);
    c += cmp2(q1.x, m) + cmp2(q1.y, m) + cmp2(q1.z, m) + cmp2(q1.w, m);
    c += cmp2(q2.x, m) + cmp2(q2.y, m) + cmp2(q2.z, m) + cmp2(q2.w, m);
    c += cmp2(q3.x, m) + cmp2(q3.y, m) + cmp2(q3.z, m) + cmp2(q3.w, m);
    c += cmp2(q4.x, m) + cmp2(q4.y, m) + cmp2(q4.z, m) + cmp2(q4.w, m);
    c += cmp2(q5.x, m) + cmp2(q5.y, m) + cmp2(q5.z, m) + cmp2(q5.w, m);
    c += cmp2(q6.x, m) + cmp2(q6.y, m) + cmp2(q6.z, m) + cmp2(q6.w, m);
    c += cmp2(q7.x, m) + cmp2(q7.y, m) + cmp2(q7.z, m) + cmp2(q7.w, m);
    c += __shfl_xor(c, 1);
    c += __shfl_xor(c, 2);
    c += __shfl_xor(c, 4);
    c += __shfl_xor(c, 8);
    c += __shfl_xor(c, 16);
    c += __shfl_xor(c, 32);
    if (c >= K_TOP) lo = m;
  }

  // prefill candidate row with threshold key, reset counter.
  // NOTE: all s.cand accesses are u16 (same type as the scatter stores) --
  // a u32-cast read here was hoisted above the scatter by the compiler
  // (strict-aliasing) in the previous round and broke correctness.
  s.cand[w][2 * lane]     = (unsigned short)lo;
  s.cand[w][2 * lane + 1] = (unsigned short)lo;
  if (lane == 0) s.cnt[w] = 0;

  // scatter strictly-greater keys (<=114 guaranteed) — wave-local LDS atomics
  #define GATH(v)                                                \
    { unsigned int _v = (v);                                     \
      if (_v > lo) {                                             \
        unsigned int _p = atomicAdd(&s.cnt[w], 1u);              \
        s.cand[w][_p] = (unsigned short)_v;                      \
      } }
  #define GATH4(q)                                               \
    GATH(q.x & 0xffffu) GATH(q.x >> 16)                          \
    GATH(q.y & 0xffffu) GATH(q.y >> 16)                          \
    GATH(q.z & 0xffffu) GATH(q.z >> 16)                          \
    GATH(q.w & 0xffffu) GATH(q.w >> 16)
  GATH4(q0) GATH4(q1) GATH4(q2) GATH4(q3)
  GATH4(q4) GATH4(q5) GATH4(q6) GATH4(q7)
  #undef GATH4
  #undef GATH

  asm volatile("" ::: "memory");  // compiler fence: scatter stores before read-back

  // rank-by-count over the 128 candidates (unique composite keys -> unique ranks)
  unsigned int k0 = s.cand[w][2 * lane];
  unsigned int k1 = s.cand[w][2 * lane + 1];
  unsigned int c0 = (k0 << 7) | (127u - (unsigned)(2 * lane));
  unsigned int c1 = (k1 << 7) | (127u - (unsigned)(2 * lane + 1));
  int r0 = 0, r1 = 0;
  #pragma unroll 1
  for (int sl = 0; sl < 64; ++sl) {
    unsigned int d0 = __shfl(c0, sl);
    unsigned int d1 = __shfl(c1, sl);
    r0 += (int)(d0 > c0) + (int)(d1 > c0);
    r1 += (int)(d0 > c1) + (int)(d1 > c1);
  }
  // out[b][rank][j] = f32(value)/256, descending by rank
  if (r0 < K_TOP)
    out[((size_t)b * K_TOP + r0) * HW + j0 + w] =
        __half2float(__ushort_as_half(key2f16(k0))) * (1.0f / 256.0f);
  if (r1 < K_TOP)
    out[((size_t)b * K_TOP + r1) * HW + j0 + w] =
        __half2float(__ushort_as_half(key2f16(k1))) * (1.0f / 256.0f);
}

extern "C" void kernel_launch(void* const* d_in, const int* in_sizes, int n_in,
                              void* d_out, int out_size, void* d_ws, size_t ws_size,
                              hipStream_t stream) {
  (void)in_sizes; (void)n_in; (void)out_size; (void)ws_size;
  const float* x = (const float*)d_in[0];
  float* out = (float*)d_out;
  float* rn = (float*)d_ws;                                      // 64 KB
  unsigned short* xnT = (unsigned short*)((char*)d_ws + 65536);  // 8 MB bf16

  norms_kernel<<<64, 256, 0, stream>>>(x, rn);
  transpose_kernel<<<1024, 256, 0, stream>>>(x, rn, xnT);
  corr_topk_kernel<<<1024, 1024, 0, stream>>>(xnT, out);
}

// Round 6
// 314.331 us; speedup vs baseline: 1.2215x; 1.1861x over previous
//
#include <hip/hip_runtime.h>
#include <hip/hip_fp16.h>

#define CH 256
#define HW 4096
#define K_TOP 115
#define COLS 16
#define CAND 128
#define CSTRIDE 4104
#define TPAD 144  // LDS tile row stride in u16: 288B = 18*16 (16B aligned), 8-bank stagger

typedef __attribute__((ext_vector_type(8))) short short8;
typedef __attribute__((ext_vector_type(4))) float f32x4;
typedef __attribute__((ext_vector_type(4))) unsigned int u32x4;

__device__ __forceinline__ unsigned short f32_to_bf16(float f) {
  union { float f; unsigned int u; } v; v.f = f;
  unsigned int r = v.u + 0x7fffu + ((v.u >> 16) & 1u);
  return (unsigned short)(r >> 16);
}

__device__ __forceinline__ unsigned int f16key(unsigned short h) {
  return (h & 0x8000u) ? (unsigned int)((unsigned short)~h)
                       : (unsigned int)(h | 0x8000u);
}

__device__ __forceinline__ unsigned short key2f16(unsigned int k) {
  return (k & 0x8000u) ? (unsigned short)(k ^ 0x8000u)
                       : (unsigned short)(~k & 0xffffu);
}

__device__ __forceinline__ int cmp2(unsigned int p, unsigned int m) {
  return (int)((p & 0xffffu) >= m) + (int)((p >> 16) >= m);
}

// ---------- kernel 1a: rn[b][p] = 1 / max(||x[b,:,p]||, eps) ----------
__global__ void norms_kernel(const float* __restrict__ x, float* __restrict__ rn) {
  int b = blockIdx.x >> 4;
  int p = ((blockIdx.x & 15) << 8) + threadIdx.x;
  const float* xb = x + (size_t)b * CH * HW + p;
  float ss = 0.f;
  #pragma unroll 8
  for (int c = 0; c < CH; ++c) { float v = xb[(size_t)c * HW]; ss += v * v; }
  rn[b * HW + p] = 1.0f / fmaxf(sqrtf(ss), 1e-12f);
}

// ---------- kernel 1b: xnT[b][p][c] = bf16(x[b][c][p] * rn[b][p]) ----------
__global__ void transpose_kernel(const float* __restrict__ x, const float* __restrict__ rn,
                                 unsigned short* __restrict__ xnT) {
  __shared__ float tile[64][65];
  int blk = blockIdx.x;
  int b = blk >> 8;
  int rem = blk & 255;
  int c0 = (rem >> 6) << 6;
  int p0 = (rem & 63) << 6;
  for (int idx = threadIdx.x; idx < 64 * 64; idx += blockDim.x) {
    int c = idx >> 6, p = idx & 63;
    tile[c][p] = x[((size_t)b * CH + c0 + c) * HW + p0 + p];
  }
  __syncthreads();
  for (int idx = threadIdx.x; idx < 64 * 64; idx += blockDim.x) {
    int p = idx >> 6, c = idx & 63;
    xnT[((size_t)b * HW + p0 + p) * CH + c0 + c] =
        f32_to_bf16(tile[c][p] * rn[b * HW + p0 + p]);
  }
}

// ---------- kernel A: one batch's Gram tile -> sortable u16 keys (row-major) ----------
// 128x128 output tile per block; 4 waves in 2x2; 4x4 fragments each; K=256.
// D row = j (A-operand), D col = i (B-operand); Gram symmetry => row-major
// keys[j][i] IS the column data the selector needs.
__launch_bounds__(256, 2)
__global__ void gram_kernel(const unsigned short* __restrict__ xnTb,
                            unsigned short* __restrict__ gkeys) {
  __shared__ unsigned short tile[128 * TPAD];
  const int tid  = threadIdx.x;
  const int lane = tid & 63, wv = tid >> 6;
  const int wj = wv >> 1, wi = wv & 1;
  const int lr = lane & 15, lk = lane >> 4;
  const int j0 = (blockIdx.x >> 5) * 128;
  const int i0 = (blockIdx.x & 31) * 128;
  const short8* x8 = (const short8*)xnTb;

  f32x4 acc[4][4];
  #pragma unroll
  for (int m = 0; m < 4; ++m)
    #pragma unroll
    for (int n = 0; n < 4; ++n) acc[m][n] = (f32x4){0.f, 0.f, 0.f, 0.f};

  const int jbase = j0 + wj * 64 + lr;
  const int ibase = i0 + wi * 64 + lr;
  #pragma unroll
  for (int kk = 0; kk < 8; ++kk) {
    short8 af[4], bf[4];
    #pragma unroll
    for (int m = 0; m < 4; ++m)
      af[m] = x8[(size_t)(jbase + m * 16) * 32 + kk * 4 + lk];
    #pragma unroll
    for (int n = 0; n < 4; ++n)
      bf[n] = x8[(size_t)(ibase + n * 16) * 32 + kk * 4 + lk];
    #pragma unroll
    for (int m = 0; m < 4; ++m)
      #pragma unroll
      for (int n = 0; n < 4; ++n)
        acc[m][n] = __builtin_amdgcn_mfma_f32_16x16x32_bf16(af[m], bf[n],
                                                            acc[m][n], 0, 0, 0);
  }

  // keys -> LDS tile[jloc][iloc]
  #pragma unroll
  for (int m = 0; m < 4; ++m) {
    #pragma unroll
    for (int n = 0; n < 4; ++n) {
      #pragma unroll
      for (int r = 0; r < 4; ++r) {
        int jloc = wj * 64 + m * 16 + lk * 4 + r;
        int iloc = wi * 64 + n * 16 + lr;
        tile[jloc * TPAD + iloc] =
            (unsigned short)f16key(__half_as_ushort(__float2half(acc[m][n][r])));
      }
    }
  }
  __syncthreads();

  // coalesced store: each row j is 256B contiguous in gkeys
  #pragma unroll
  for (int itr = 0; itr < 8; ++itr) {
    int idx = itr * 256 + tid;
    int row = idx >> 4, ch = idx & 15;
    u32x4 v = *(const u32x4*)&tile[row * TPAD + ch * 8];
    *(u32x4*)(gkeys + (size_t)(j0 + row) * HW + i0 + ch * 8) = v;
  }
}

// ---------- kernel B: per-column top-115 from the key matrix ----------
// One wave per column; high occupancy hides the serial binary-search chains.
__launch_bounds__(256, 4)
__global__ void select_kernel(const unsigned short* __restrict__ gkeys,
                              float* __restrict__ out, int b) {
  __shared__ unsigned short cand[4][CAND];
  __shared__ unsigned int cnt[4];
  const int tid  = threadIdx.x;
  const int lane = tid & 63, wv = tid >> 6;
  const int j = blockIdx.x * 4 + wv;
  const u32x4* cp = (const u32x4*)(gkeys + (size_t)j * HW);

  u32x4 q0 = cp[0 * 64 + lane];
  u32x4 q1 = cp[1 * 64 + lane];
  u32x4 q2 = cp[2 * 64 + lane];
  u32x4 q3 = cp[3 * 64 + lane];
  u32x4 q4 = cp[4 * 64 + lane];
  u32x4 q5 = cp[5 * 64 + lane];
  u32x4 q6 = cp[6 * 64 + lane];
  u32x4 q7 = cp[7 * 64 + lane];

  // binary search: lo = max v with #{key >= v} >= 115 (exact threshold key)
  unsigned int lo = 0;
  #pragma unroll 1
  for (int bit = 15; bit >= 0; --bit) {
    const unsigned int m = lo | (1u << bit);
    int c = 0;
    c += cmp2(q0.x, m) + cmp2(q0.y, m) + cmp2(q0.z, m) + cmp2(q0.w, m);
    c += cmp2(q1.x, m) + cmp2(q1.y, m) + cmp2(q1.z, m) + cmp2(q1.w, m);
    c += cmp2(q2.x, m) + cmp2(q2.y, m) + cmp2(q2.z, m) + cmp2(q2.w, m);
    c += cmp2(q3.x, m) + cmp2(q3.y, m) + cmp2(q3.z, m) + cmp2(q3.w, m);
    c += cmp2(q4.x, m) + cmp2(q4.y, m) + cmp2(q4.z, m) + cmp2(q4.w, m);
    c += cmp2(q5.x, m) + cmp2(q5.y, m) + cmp2(q5.z, m) + cmp2(q5.w, m);
    c += cmp2(q6.x, m) + cmp2(q6.y, m) + cmp2(q6.z, m) + cmp2(q6.w, m);
    c += cmp2(q7.x, m) + cmp2(q7.y, m) + cmp2(q7.z, m) + cmp2(q7.w, m);
    c += __shfl_xor(c, 1);
    c += __shfl_xor(c, 2);
    c += __shfl_xor(c, 4);
    c += __shfl_xor(c, 8);
    c += __shfl_xor(c, 16);
    c += __shfl_xor(c, 32);
    if (c >= K_TOP) lo = m;
  }

  // prefill candidates with threshold key (u16-typed accesses only — TBAA!)
  cand[wv][2 * lane]     = (unsigned short)lo;
  cand[wv][2 * lane + 1] = (unsigned short)lo;
  if (lane == 0) cnt[wv] = 0;

  #define GATH(v)                                                \
    { unsigned int _v = (v);                                     \
      if (_v > lo) {                                             \
        unsigned int _p = atomicAdd(&cnt[wv], 1u);               \
        cand[wv][_p] = (unsigned short)_v;                       \
      } }
  #define GATH4(q)                                               \
    GATH(q.x & 0xffffu) GATH(q.x >> 16)                          \
    GATH(q.y & 0xffffu) GATH(q.y >> 16)                          \
    GATH(q.z & 0xffffu) GATH(q.z >> 16)                          \
    GATH(q.w & 0xffffu) GATH(q.w >> 16)
  GATH4(q0) GATH4(q1) GATH4(q2) GATH4(q3)
  GATH4(q4) GATH4(q5) GATH4(q6) GATH4(q7)
  #undef GATH4
  #undef GATH

  asm volatile("" ::: "memory");  // scatter stores before read-back

  // rank-by-count (unique composite keys -> unique ranks)
  unsigned int k0 = cand[wv][2 * lane];
  unsigned int k1 = cand[wv][2 * lane + 1];
  unsigned int c0 = (k0 << 7) | (127u - (unsigned)(2 * lane));
  unsigned int c1 = (k1 << 7) | (127u - (unsigned)(2 * lane + 1));
  int r0 = 0, r1 = 0;
  #pragma unroll 1
  for (int sl = 0; sl < 64; ++sl) {
    unsigned int d0 = __shfl(c0, sl);
    unsigned int d1 = __shfl(c1, sl);
    r0 += (int)(d0 > c0) + (int)(d1 > c0);
    r1 += (int)(d0 > c1) + (int)(d1 > c1);
  }
  if (r0 < K_TOP)
    out[((size_t)b * K_TOP + r0) * HW + j] =
        __half2float(__ushort_as_half(key2f16(k0))) * (1.0f / 256.0f);
  if (r1 < K_TOP)
    out[((size_t)b * K_TOP + r1) * HW + j] =
        __half2float(__ushort_as_half(key2f16(k1))) * (1.0f / 256.0f);
}

// ================= fallback: validated R5 fused kernel =================
struct K2S {
  unsigned short colkeys[COLS][CSTRIDE];
  unsigned short cand[COLS][CAND];
  unsigned int   cnt[COLS];
};

__launch_bounds__(1024, 4)
__global__ void corr_topk_kernel(const unsigned short* __restrict__ xnT,
                                 float* __restrict__ out) {
  __shared__ __align__(16) K2S s;
  const int tid  = threadIdx.x;
  const int lane = tid & 63;
  const int w    = tid >> 6;
  const int lr   = lane & 15;
  const int lk   = lane >> 4;
  const int blk = blockIdx.x;
  const int xcd = blk & 7;
  const int b   = xcd >> 1;
  const int jt  = ((xcd & 1) << 7) + (blk >> 3);
  const int j0  = jt * COLS;
  const short8* x8 = (const short8*)(xnT + (size_t)b * HW * CH);

  short8 bfrag[8];
  #pragma unroll
  for (int kk = 0; kk < 8; ++kk)
    bfrag[kk] = x8[(j0 + lr) * 32 + kk * 4 + lk];

  for (int t = 0; t < 16; ++t) {
    const int i0 = (w + 16 * t) * 16;
    f32x4 acc = {0.f, 0.f, 0.f, 0.f};
    #pragma unroll
    for (int kk = 0; kk < 8; ++kk) {
      short8 afrag = x8[(i0 + lr) * 32 + kk * 4 + lk];
      acc = __builtin_amdgcn_mfma_f32_16x16x32_bf16(afrag, bfrag[kk], acc, 0, 0, 0);
    }
    unsigned long long k0 = f16key(__half_as_ushort(__float2half(acc[0])));
    unsigned long long k1 = f16key(__half_as_ushort(__float2half(acc[1])));
    unsigned long long k2 = f16key(__half_as_ushort(__float2half(acc[2])));
    unsigned long long k3 = f16key(__half_as_ushort(__float2half(acc[3])));
    *(unsigned long long*)&s.colkeys[lr][i0 + lk * 4] =
        k0 | (k1 << 16) | (k2 << 32) | (k3 << 48);
  }
  __syncthreads();

  const u32x4* cp = (const u32x4*)&s.colkeys[w][0];
  u32x4 q0 = cp[0 * 64 + lane];
  u32x4 q1 = cp[1 * 64 + lane];
  u32x4 q2 = cp[2 * 64 + lane];
  u32x4 q3 = cp[3 * 64 + lane];
  u32x4 q4 = cp[4 * 64 + lane];
  u32x4 q5 = cp[5 * 64 + lane];
  u32x4 q6 = cp[6 * 64 + lane];
  u32x4 q7 = cp[7 * 64 + lane];

  unsigned int lo = 0;
  #pragma unroll 1
  for (int bit = 15; bit >= 0; --bit) {
    const unsigned int m = lo | (1u << bit);
    int c = 0;
    c += cmp2(q0.x, m) + cmp2(q0.y, m) + cmp2(q0.z, m) + cmp2(q0.w, m);
    c += cmp2(q1.x, m) + cmp2(q1.y, m) + cmp2(q1.z, m) + cmp2(q1.w, m);
    c += cmp2(q2.x, m) + cmp2(q2.y, m) + cmp2(q2.z, m) + cmp2(q2.w, m);
    c += cmp2(q3.x, m) + cmp2(q3.y, m) + cmp2(q3.z, m) + cmp2(q3.w, m);
    c += cmp2(q4.x, m) + cmp2(q4.y, m) + cmp2(q4.z, m) + cmp2(q4.w, m);
    c += cmp2(q5.x, m) + cmp2(q5.y, m) + cmp2(q5.z, m) + cmp2(q5.w, m);
    c += cmp2(q6.x, m) + cmp2(q6.y, m) + cmp2(q6.z, m) + cmp2(q6.w, m);
    c += cmp2(q7.x, m) + cmp2(q7.y, m) + cmp2(q7.z, m) + cmp2(q7.w, m);
    c += __shfl_xor(c, 1);
    c += __shfl_xor(c, 2);
    c += __shfl_xor(c, 4);
    c += __shfl_xor(c, 8);
    c += __shfl_xor(c, 16);
    c += __shfl_xor(c, 32);
    if (c >= K_TOP) lo = m;
  }

  s.cand[w][2 * lane]     = (unsigned short)lo;
  s.cand[w][2 * lane + 1] = (unsigned short)lo;
  if (lane == 0) s.cnt[w] = 0;

  #define GATH(v)                                                \
    { unsigned int _v = (v);                                     \
      if (_v > lo) {                                             \
        unsigned int _p = atomicAdd(&s.cnt[w], 1u);              \
        s.cand[w][_p] = (unsigned short)_v;                      \
      } }
  #define GATH4(q)                                               \
    GATH(q.x & 0xffffu) GATH(q.x >> 16)                          \
    GATH(q.y & 0xffffu) GATH(q.y >> 16)                          \
    GATH(q.z & 0xffffu) GATH(q.z >> 16)                          \
    GATH(q.w & 0xffffu) GATH(q.w >> 16)
  GATH4(q0) GATH4(q1) GATH4(q2) GATH4(q3)
  GATH4(q4) GATH4(q5) GATH4(q6) GATH4(q7)
  #undef GATH4
  #undef GATH

  asm volatile("" ::: "memory");

  unsigned int k0 = s.cand[w][2 * lane];
  unsigned int k1 = s.cand[w][2 * lane + 1];
  unsigned int c0 = (k0 << 7) | (127u - (unsigned)(2 * lane));
  unsigned int c1 = (k1 << 7) | (127u - (unsigned)(2 * lane + 1));
  int r0 = 0, r1 = 0;
  #pragma unroll 1
  for (int sl = 0; sl < 64; ++sl) {
    unsigned int d0 = __shfl(c0, sl);
    unsigned int d1 = __shfl(c1, sl);
    r0 += (int)(d0 > c0) + (int)(d1 > c0);
    r1 += (int)(d0 > c1) + (int)(d1 > c1);
  }
  if (r0 < K_TOP)
    out[((size_t)b * K_TOP + r0) * HW + j0 + w] =
        __half2float(__ushort_as_half(key2f16(k0))) * (1.0f / 256.0f);
  if (r1 < K_TOP)
    out[((size_t)b * K_TOP + r1) * HW + j0 + w] =
        __half2float(__ushort_as_half(key2f16(k1))) * (1.0f / 256.0f);
}

extern "C" void kernel_launch(void* const* d_in, const int* in_sizes, int n_in,
                              void* d_out, int out_size, void* d_ws, size_t ws_size,
                              hipStream_t stream) {
  (void)in_sizes; (void)n_in; (void)out_size;
  const float* x = (const float*)d_in[0];
  float* out = (float*)d_out;
  float* rn = (float*)d_ws;                                       // 64 KB
  unsigned short* xnT = (unsigned short*)((char*)d_ws + 65536);   // 8 MB bf16
  const size_t GK_OFF = 65536 + (size_t)8 * 1024 * 1024;          // 8.06 MB
  const size_t NEED = GK_OFF + (size_t)HW * HW * 2;               // +32 MB keys

  norms_kernel<<<64, 256, 0, stream>>>(x, rn);
  transpose_kernel<<<1024, 256, 0, stream>>>(x, rn, xnT);

  if (ws_size >= NEED) {
    unsigned short* gkeys = (unsigned short*)((char*)d_ws + GK_OFF);
    for (int b = 0; b < 4; ++b) {
      gram_kernel<<<1024, 256, 0, stream>>>(xnT + (size_t)b * HW * CH, gkeys);
      select_kernel<<<1024, 256, 0, stream>>>(gkeys, out, b);
    }
  } else {
    corr_topk_kernel<<<1024, 1024, 0, stream>>>(xnT, out);
  }
}

// Round 7
// 243.995 us; speedup vs baseline: 1.5736x; 1.2883x over previous
//
#include <hip/hip_runtime.h>
#include <hip/hip_fp16.h>

#define CH 256
#define HW 4096
#define K_TOP 115
#define COLS 16
#define CAND 128
#define CSTRIDE 4104
#define TPAD 152  // u16 row stride: 304B = 76 words; 4-row offset = 16 mod 32 -> 2-way (free); rows 16B-aligned

typedef __attribute__((ext_vector_type(8))) short short8;
typedef __attribute__((ext_vector_type(4))) float f32x4;
typedef __attribute__((ext_vector_type(4))) unsigned int u32x4;

__device__ __forceinline__ unsigned short f32_to_bf16(float f) {
  union { float f; unsigned int u; } v; v.f = f;
  unsigned int r = v.u + 0x7fffu + ((v.u >> 16) & 1u);
  return (unsigned short)(r >> 16);
}

__device__ __forceinline__ unsigned int f16key(unsigned short h) {
  return (h & 0x8000u) ? (unsigned int)((unsigned short)~h)
                       : (unsigned int)(h | 0x8000u);
}

__device__ __forceinline__ unsigned short key2f16(unsigned int k) {
  return (k & 0x8000u) ? (unsigned short)(k ^ 0x8000u)
                       : (unsigned short)(~k & 0xffffu);
}

__device__ __forceinline__ int cmp2(unsigned int p, unsigned int m) {
  return (int)((p & 0xffffu) >= m) + (int)((p >> 16) >= m);
}

// ---------- kernel 1a: rn[b][p] = 1 / max(||x[b,:,p]||, eps) ----------
__global__ void norms_kernel(const float* __restrict__ x, float* __restrict__ rn) {
  int b = blockIdx.x >> 4;
  int p = ((blockIdx.x & 15) << 8) + threadIdx.x;
  const float* xb = x + (size_t)b * CH * HW + p;
  float ss = 0.f;
  #pragma unroll 8
  for (int c = 0; c < CH; ++c) { float v = xb[(size_t)c * HW]; ss += v * v; }
  rn[b * HW + p] = 1.0f / fmaxf(sqrtf(ss), 1e-12f);
}

// ---------- kernel 1b: xnT[b][p][c] = bf16(x[b][c][p] * rn[b][p]) ----------
__global__ void transpose_kernel(const float* __restrict__ x, const float* __restrict__ rn,
                                 unsigned short* __restrict__ xnT) {
  __shared__ float tile[64][65];
  int blk = blockIdx.x;
  int b = blk >> 8;
  int rem = blk & 255;
  int c0 = (rem >> 6) << 6;
  int p0 = (rem & 63) << 6;
  for (int idx = threadIdx.x; idx < 64 * 64; idx += blockDim.x) {
    int c = idx >> 6, p = idx & 63;
    tile[c][p] = x[((size_t)b * CH + c0 + c) * HW + p0 + p];
  }
  __syncthreads();
  for (int idx = threadIdx.x; idx < 64 * 64; idx += blockDim.x) {
    int p = idx >> 6, c = idx & 63;
    xnT[((size_t)b * HW + p0 + p) * CH + c0 + c] =
        f32_to_bf16(tile[c][p] * rn[b * HW + p0 + p]);
  }
}

// ---------- kernel A: Gram tiles -> sortable u16 keys (row-major per batch) ----------
// grid = nb*1024 blocks; blockIdx>>10 selects batch. 128x128 tile per block;
// 4 waves 2x2; 4x4 fragments; K=256 unrolled. D row = j, D col = i; Gram
// symmetry => row-major keys[j][i] IS column j's data.
__launch_bounds__(256, 4)
__global__ void gram_kernel(const unsigned short* __restrict__ xnT,
                            unsigned short* __restrict__ gkeys) {
  __shared__ unsigned short tile[128 * TPAD];
  const int tid  = threadIdx.x;
  const int lane = tid & 63, wv = tid >> 6;
  const int wj = wv >> 1, wi = wv & 1;
  const int lr = lane & 15, lk = lane >> 4;
  const int bb  = blockIdx.x >> 10;
  const int rem = blockIdx.x & 1023;
  const int j0 = (rem >> 5) * 128;
  const int i0 = (rem & 31) * 128;
  const short8* x8 = (const short8*)(xnT + (size_t)bb * HW * CH);
  unsigned short* gk = gkeys + (size_t)bb * HW * HW;

  f32x4 acc[4][4];
  #pragma unroll
  for (int m = 0; m < 4; ++m)
    #pragma unroll
    for (int n = 0; n < 4; ++n) acc[m][n] = (f32x4){0.f, 0.f, 0.f, 0.f};

  const int jbase = j0 + wj * 64 + lr;
  const int ibase = i0 + wi * 64 + lr;
  #pragma unroll
  for (int kk = 0; kk < 8; ++kk) {
    short8 af[4], bf[4];
    #pragma unroll
    for (int m = 0; m < 4; ++m)
      af[m] = x8[(size_t)(jbase + m * 16) * 32 + kk * 4 + lk];
    #pragma unroll
    for (int n = 0; n < 4; ++n)
      bf[n] = x8[(size_t)(ibase + n * 16) * 32 + kk * 4 + lk];
    #pragma unroll
    for (int m = 0; m < 4; ++m)
      #pragma unroll
      for (int n = 0; n < 4; ++n)
        acc[m][n] = __builtin_amdgcn_mfma_f32_16x16x32_bf16(af[m], bf[n],
                                                            acc[m][n], 0, 0, 0);
  }

  // keys -> LDS tile[jloc][iloc]
  #pragma unroll
  for (int m = 0; m < 4; ++m) {
    #pragma unroll
    for (int n = 0; n < 4; ++n) {
      #pragma unroll
      for (int r = 0; r < 4; ++r) {
        int jloc = wj * 64 + m * 16 + lk * 4 + r;
        int iloc = wi * 64 + n * 16 + lr;
        tile[jloc * TPAD + iloc] =
            (unsigned short)f16key(__half_as_ushort(__float2half(acc[m][n][r])));
      }
    }
  }
  __syncthreads();

  // coalesced store: each row j is 256B contiguous in gkeys
  #pragma unroll
  for (int itr = 0; itr < 8; ++itr) {
    int idx = itr * 256 + tid;
    int row = idx >> 4, ch = idx & 15;
    u32x4 v = *(const u32x4*)&tile[row * TPAD + ch * 8];
    *(u32x4*)(gk + (size_t)(j0 + row) * HW + i0 + ch * 8) = v;
  }
}

// ---------- kernel B: per-column top-115 from the key matrix ----------
// grid = nb*1024; blockIdx>>10 selects batch (b_base + bb for per-batch mode).
__launch_bounds__(256, 4)
__global__ void select_kernel(const unsigned short* __restrict__ gkeys,
                              float* __restrict__ out, int b_base) {
  __shared__ unsigned short cand[4][CAND];
  __shared__ unsigned int cnt[4];
  const int tid  = threadIdx.x;
  const int lane = tid & 63, wv = tid >> 6;
  const int bb = blockIdx.x >> 10;
  const int b  = b_base + bb;
  const int j  = (blockIdx.x & 1023) * 4 + wv;
  const u32x4* cp = (const u32x4*)(gkeys + (size_t)bb * HW * HW + (size_t)j * HW);

  u32x4 q0 = cp[0 * 64 + lane];
  u32x4 q1 = cp[1 * 64 + lane];
  u32x4 q2 = cp[2 * 64 + lane];
  u32x4 q3 = cp[3 * 64 + lane];
  u32x4 q4 = cp[4 * 64 + lane];
  u32x4 q5 = cp[5 * 64 + lane];
  u32x4 q6 = cp[6 * 64 + lane];
  u32x4 q7 = cp[7 * 64 + lane];

  // binary search: lo = max v with #{key >= v} >= 115 (exact threshold key)
  unsigned int lo = 0;
  #pragma unroll 1
  for (int bit = 15; bit >= 0; --bit) {
    const unsigned int m = lo | (1u << bit);
    int c = 0;
    c += cmp2(q0.x, m) + cmp2(q0.y, m) + cmp2(q0.z, m) + cmp2(q0.w, m);
    c += cmp2(q1.x, m) + cmp2(q1.y, m) + cmp2(q1.z, m) + cmp2(q1.w, m);
    c += cmp2(q2.x, m) + cmp2(q2.y, m) + cmp2(q2.z, m) + cmp2(q2.w, m);
    c += cmp2(q3.x, m) + cmp2(q3.y, m) + cmp2(q3.z, m) + cmp2(q3.w, m);
    c += cmp2(q4.x, m) + cmp2(q4.y, m) + cmp2(q4.z, m) + cmp2(q4.w, m);
    c += cmp2(q5.x, m) + cmp2(q5.y, m) + cmp2(q5.z, m) + cmp2(q5.w, m);
    c += cmp2(q6.x, m) + cmp2(q6.y, m) + cmp2(q6.z, m) + cmp2(q6.w, m);
    c += cmp2(q7.x, m) + cmp2(q7.y, m) + cmp2(q7.z, m) + cmp2(q7.w, m);
    c += __shfl_xor(c, 1);
    c += __shfl_xor(c, 2);
    c += __shfl_xor(c, 4);
    c += __shfl_xor(c, 8);
    c += __shfl_xor(c, 16);
    c += __shfl_xor(c, 32);
    if (c >= K_TOP) lo = m;
  }

  // prefill candidates with threshold key (u16-typed accesses only — TBAA!)
  cand[wv][2 * lane]     = (unsigned short)lo;
  cand[wv][2 * lane + 1] = (unsigned short)lo;
  if (lane == 0) cnt[wv] = 0;

  #define GATH(v)                                                \
    { unsigned int _v = (v);                                     \
      if (_v > lo) {                                             \
        unsigned int _p = atomicAdd(&cnt[wv], 1u);               \
        cand[wv][_p] = (unsigned short)_v;                       \
      } }
  #define GATH4(q)                                               \
    GATH(q.x & 0xffffu) GATH(q.x >> 16)                          \
    GATH(q.y & 0xffffu) GATH(q.y >> 16)                          \
    GATH(q.z & 0xffffu) GATH(q.z >> 16)                          \
    GATH(q.w & 0xffffu) GATH(q.w >> 16)
  GATH4(q0) GATH4(q1) GATH4(q2) GATH4(q3)
  GATH4(q4) GATH4(q5) GATH4(q6) GATH4(q7)
  #undef GATH4
  #undef GATH

  asm volatile("" ::: "memory");  // scatter stores before read-back

  // rank-by-count (unique composite keys -> unique ranks)
  unsigned int k0 = cand[wv][2 * lane];
  unsigned int k1 = cand[wv][2 * lane + 1];
  unsigned int c0 = (k0 << 7) | (127u - (unsigned)(2 * lane));
  unsigned int c1 = (k1 << 7) | (127u - (unsigned)(2 * lane + 1));
  int r0 = 0, r1 = 0;
  #pragma unroll 1
  for (int sl = 0; sl < 64; ++sl) {
    unsigned int d0 = __shfl(c0, sl);
    unsigned int d1 = __shfl(c1, sl);
    r0 += (int)(d0 > c0) + (int)(d1 > c0);
    r1 += (int)(d0 > c1) + (int)(d1 > c1);
  }
  if (r0 < K_TOP)
    out[((size_t)b * K_TOP + r0) * HW + j] =
        __half2float(__ushort_as_half(key2f16(k0))) * (1.0f / 256.0f);
  if (r1 < K_TOP)
    out[((size_t)b * K_TOP + r1) * HW + j] =
        __half2float(__ushort_as_half(key2f16(k1))) * (1.0f / 256.0f);
}

// ================= fallback: validated R5 fused kernel =================
struct K2S {
  unsigned short colkeys[COLS][CSTRIDE];
  unsigned short cand[COLS][CAND];
  unsigned int   cnt[COLS];
};

__launch_bounds__(1024, 4)
__global__ void corr_topk_kernel(const unsigned short* __restrict__ xnT,
                                 float* __restrict__ out) {
  __shared__ __align__(16) K2S s;
  const int tid  = threadIdx.x;
  const int lane = tid & 63;
  const int w    = tid >> 6;
  const int lr   = lane & 15;
  const int lk   = lane >> 4;
  const int blk = blockIdx.x;
  const int xcd = blk & 7;
  const int b   = xcd >> 1;
  const int jt  = ((xcd & 1) << 7) + (blk >> 3);
  const int j0  = jt * COLS;
  const short8* x8 = (const short8*)(xnT + (size_t)b * HW * CH);

  short8 bfrag[8];
  #pragma unroll
  for (int kk = 0; kk < 8; ++kk)
    bfrag[kk] = x8[(j0 + lr) * 32 + kk * 4 + lk];

  for (int t = 0; t < 16; ++t) {
    const int i0 = (w + 16 * t) * 16;
    f32x4 acc = {0.f, 0.f, 0.f, 0.f};
    #pragma unroll
    for (int kk = 0; kk < 8; ++kk) {
      short8 afrag = x8[(i0 + lr) * 32 + kk * 4 + lk];
      acc = __builtin_amdgcn_mfma_f32_16x16x32_bf16(afrag, bfrag[kk], acc, 0, 0, 0);
    }
    unsigned long long k0 = f16key(__half_as_ushort(__float2half(acc[0])));
    unsigned long long k1 = f16key(__half_as_ushort(__float2half(acc[1])));
    unsigned long long k2 = f16key(__half_as_ushort(__float2half(acc[2])));
    unsigned long long k3 = f16key(__half_as_ushort(__float2half(acc[3])));
    *(unsigned long long*)&s.colkeys[lr][i0 + lk * 4] =
        k0 | (k1 << 16) | (k2 << 32) | (k3 << 48);
  }
  __syncthreads();

  const u32x4* cp = (const u32x4*)&s.colkeys[w][0];
  u32x4 q0 = cp[0 * 64 + lane];
  u32x4 q1 = cp[1 * 64 + lane];
  u32x4 q2 = cp[2 * 64 + lane];
  u32x4 q3 = cp[3 * 64 + lane];
  u32x4 q4 = cp[4 * 64 + lane];
  u32x4 q5 = cp[5 * 64 + lane];
  u32x4 q6 = cp[6 * 64 + lane];
  u32x4 q7 = cp[7 * 64 + lane];

  unsigned int lo = 0;
  #pragma unroll 1
  for (int bit = 15; bit >= 0; --bit) {
    const unsigned int m = lo | (1u << bit);
    int c = 0;
    c += cmp2(q0.x, m) + cmp2(q0.y, m) + cmp2(q0.z, m) + cmp2(q0.w, m);
    c += cmp2(q1.x, m) + cmp2(q1.y, m) + cmp2(q1.z, m) + cmp2(q1.w, m);
    c += cmp2(q2.x, m) + cmp2(q2.y, m) + cmp2(q2.z, m) + cmp2(q2.w, m);
    c += cmp2(q3.x, m) + cmp2(q3.y, m) + cmp2(q3.z, m) + cmp2(q3.w, m);
    c += cmp2(q4.x, m) + cmp2(q4.y, m) + cmp2(q4.z, m) + cmp2(q4.w, m);
    c += cmp2(q5.x, m) + cmp2(q5.y, m) + cmp2(q5.z, m) + cmp2(q5.w, m);
    c += cmp2(q6.x, m) + cmp2(q6.y, m) + cmp2(q6.z, m) + cmp2(q6.w, m);
    c += cmp2(q7.x, m) + cmp2(q7.y, m) + cmp2(q7.z, m) + cmp2(q7.w, m);
    c += __shfl_xor(c, 1);
    c += __shfl_xor(c, 2);
    c += __shfl_xor(c, 4);
    c += __shfl_xor(c, 8);
    c += __shfl_xor(c, 16);
    c += __shfl_xor(c, 32);
    if (c >= K_TOP) lo = m;
  }

  s.cand[w][2 * lane]     = (unsigned short)lo;
  s.cand[w][2 * lane + 1] = (unsigned short)lo;
  if (lane == 0) s.cnt[w] = 0;

  #define GATH(v)                                                \
    { unsigned int _v = (v);                                     \
      if (_v > lo) {                                             \
        unsigned int _p = atomicAdd(&s.cnt[w], 1u);              \
        s.cand[w][_p] = (unsigned short)_v;                      \
      } }
  #define GATH4(q)                                               \
    GATH(q.x & 0xffffu) GATH(q.x >> 16)                          \
    GATH(q.y & 0xffffu) GATH(q.y >> 16)                          \
    GATH(q.z & 0xffffu) GATH(q.z >> 16)                          \
    GATH(q.w & 0xffffu) GATH(q.w >> 16)
  GATH4(q0) GATH4(q1) GATH4(q2) GATH4(q3)
  GATH4(q4) GATH4(q5) GATH4(q6) GATH4(q7)
  #undef GATH4
  #undef GATH

  asm volatile("" ::: "memory");

  unsigned int k0 = s.cand[w][2 * lane];
  unsigned int k1 = s.cand[w][2 * lane + 1];
  unsigned int c0 = (k0 << 7) | (127u - (unsigned)(2 * lane));
  unsigned int c1 = (k1 << 7) | (127u - (unsigned)(2 * lane + 1));
  int r0 = 0, r1 = 0;
  #pragma unroll 1
  for (int sl = 0; sl < 64; ++sl) {
    unsigned int d0 = __shfl(c0, sl);
    unsigned int d1 = __shfl(c1, sl);
    r0 += (int)(d0 > c0) + (int)(d1 > c0);
    r1 += (int)(d0 > c1) + (int)(d1 > c1);
  }
  if (r0 < K_TOP)
    out[((size_t)b * K_TOP + r0) * HW + j0 + w] =
        __half2float(__ushort_as_half(key2f16(k0))) * (1.0f / 256.0f);
  if (r1 < K_TOP)
    out[((size_t)b * K_TOP + r1) * HW + j0 + w] =
        __half2float(__ushort_as_half(key2f16(k1))) * (1.0f / 256.0f);
}

extern "C" void kernel_launch(void* const* d_in, const int* in_sizes, int n_in,
                              void* d_out, int out_size, void* d_ws, size_t ws_size,
                              hipStream_t stream) {
  (void)in_sizes; (void)n_in; (void)out_size;
  const float* x = (const float*)d_in[0];
  float* out = (float*)d_out;
  float* rn = (float*)d_ws;                                       // 64 KB
  unsigned short* xnT = (unsigned short*)((char*)d_ws + 65536);   // 8 MB bf16
  const size_t GK_OFF  = 65536 + (size_t)8 * 1024 * 1024;
  const size_t ONE     = (size_t)HW * HW * 2;                     // 32 MB / batch
  const size_t NEED_1  = GK_OFF + ONE;
  const size_t NEED_4  = GK_OFF + 4 * ONE;                        // 136 MB

  norms_kernel<<<64, 256, 0, stream>>>(x, rn);
  transpose_kernel<<<1024, 256, 0, stream>>>(x, rn, xnT);

  if (ws_size >= NEED_4) {
    unsigned short* gkeys = (unsigned short*)((char*)d_ws + GK_OFF);
    gram_kernel<<<4096, 256, 0, stream>>>(xnT, gkeys);
    select_kernel<<<4096, 256, 0, stream>>>(gkeys, out, 0);
  } else if (ws_size >= NEED_1) {
    unsigned short* gkeys = (unsigned short*)((char*)d_ws + GK_OFF);
    for (int b = 0; b < 4; ++b) {
      gram_kernel<<<1024, 256, 0, stream>>>(xnT + (size_t)b * HW * CH, gkeys);
      select_kernel<<<1024, 256, 0, stream>>>(gkeys, out, b);
    }
  } else {
    corr_topk_kernel<<<1024, 1024, 0, stream>>>(xnT, out);
  }
}

// Round 8
// 196.589 us; speedup vs baseline: 1.9530x; 1.2411x over previous
//
#include <hip/hip_runtime.h>
#include <hip/hip_fp16.h>

#define CH 256
#define HW 4096
#define K_TOP 115
#define CAND 128
#define TPAD 152   // u16 row stride: 304B; 4-row offset = 16 mod 32 -> 2-way (free); rows 16B-aligned
#define NTRI 528   // 32*33/2 upper-triangle 128x128 tiles per batch

typedef __attribute__((ext_vector_type(8))) short short8;
typedef __attribute__((ext_vector_type(4))) float f32x4;
typedef __attribute__((ext_vector_type(4))) unsigned int u32x4;

__device__ __forceinline__ unsigned short f32_to_bf16(float f) {
  union { float f; unsigned int u; } v; v.f = f;
  unsigned int r = v.u + 0x7fffu + ((v.u >> 16) & 1u);
  return (unsigned short)(r >> 16);
}

__device__ __forceinline__ unsigned int f16key(unsigned short h) {
  return (h & 0x8000u) ? (unsigned int)((unsigned short)~h)
                       : (unsigned int)(h | 0x8000u);
}

__device__ __forceinline__ unsigned short key2f16(unsigned int k) {
  return (k & 0x8000u) ? (unsigned short)(k ^ 0x8000u)
                       : (unsigned short)(~k & 0xffffu);
}

__device__ __forceinline__ int cmp2(unsigned int p, unsigned int m) {
  return (int)((p & 0xffffu) >= m) + (int)((p >> 16) >= m);
}

// ---------- kernel 1a: rn[b][p] = 1 / max(||x[b,:,p]||, eps) ----------
__global__ void norms_kernel(const float* __restrict__ x, float* __restrict__ rn) {
  int b = blockIdx.x >> 4;
  int p = ((blockIdx.x & 15) << 8) + threadIdx.x;
  const float* xb = x + (size_t)b * CH * HW + p;
  float ss = 0.f;
  #pragma unroll 8
  for (int c = 0; c < CH; ++c) { float v = xb[(size_t)c * HW]; ss += v * v; }
  rn[b * HW + p] = 1.0f / fmaxf(sqrtf(ss), 1e-12f);
}

// ---------- kernel 1b: xnT[b][p][c] = bf16(x[b][c][p] * rn[b][p]) ----------
__global__ void transpose_kernel(const float* __restrict__ x, const float* __restrict__ rn,
                                 unsigned short* __restrict__ xnT) {
  __shared__ float tile[64][65];
  int blk = blockIdx.x;
  int b = blk >> 8;
  int rem = blk & 255;
  int c0 = (rem >> 6) << 6;
  int p0 = (rem & 63) << 6;
  for (int idx = threadIdx.x; idx < 64 * 64; idx += blockDim.x) {
    int c = idx >> 6, p = idx & 63;
    tile[c][p] = x[((size_t)b * CH + c0 + c) * HW + p0 + p];
  }
  __syncthreads();
  for (int idx = threadIdx.x; idx < 64 * 64; idx += blockDim.x) {
    int p = idx >> 6, c = idx & 63;
    xnT[((size_t)b * HW + p0 + p) * CH + c0 + c] =
        f32_to_bf16(tile[c][p] * rn[b * HW + p0 + p]);
  }
}

// ---------- kernel A: symmetric Gram -> u16 keys (row-major per batch) ----------
// grid = nb*NTRI; only upper-triangle tiles (it >= jt) computed; off-diagonal
// tiles stored twice (normal + transposed via LDS refill). 128x128 tile,
// 4 waves 2x2, 4x4 fragments, K=256 unrolled.
__launch_bounds__(256, 4)
__global__ void gram_kernel(const unsigned short* __restrict__ xnT,
                            unsigned short* __restrict__ gkeys) {
  __shared__ unsigned short tile[128 * TPAD];
  const int tid  = threadIdx.x;
  const int lane = tid & 63, wv = tid >> 6;
  const int wj = wv >> 1, wi = wv & 1;
  const int lr = lane & 15, lk = lane >> 4;

  const int bb = blockIdx.x / NTRI;
  const int t  = blockIdx.x - bb * NTRI;
  // triangular decode: it = largest with it*(it+1)/2 <= t
  int it = (int)((sqrtf(8.0f * (float)t + 1.0f) - 1.0f) * 0.5f);
  while (((it + 1) * (it + 2)) / 2 <= t) ++it;
  while ((it * (it + 1)) / 2 > t) --it;
  const int jt = t - (it * (it + 1)) / 2;  // jt <= it
  const int j0 = jt * 128, i0 = it * 128;

  const short8* x8 = (const short8*)(xnT + (size_t)bb * HW * CH);
  unsigned short* gk = gkeys + (size_t)bb * HW * HW;

  f32x4 acc[4][4];
  #pragma unroll
  for (int m = 0; m < 4; ++m)
    #pragma unroll
    for (int n = 0; n < 4; ++n) acc[m][n] = (f32x4){0.f, 0.f, 0.f, 0.f};

  const int jbase = j0 + wj * 64 + lr;
  const int ibase = i0 + wi * 64 + lr;
  #pragma unroll
  for (int kk = 0; kk < 8; ++kk) {
    short8 af[4], bf[4];
    #pragma unroll
    for (int m = 0; m < 4; ++m)
      af[m] = x8[(size_t)(jbase + m * 16) * 32 + kk * 4 + lk];
    #pragma unroll
    for (int n = 0; n < 4; ++n)
      bf[n] = x8[(size_t)(ibase + n * 16) * 32 + kk * 4 + lk];
    #pragma unroll
    for (int m = 0; m < 4; ++m)
      #pragma unroll
      for (int n = 0; n < 4; ++n)
        acc[m][n] = __builtin_amdgcn_mfma_f32_16x16x32_bf16(af[m], bf[n],
                                                            acc[m][n], 0, 0, 0);
  }

  // phase 1: keys -> tile[jloc][iloc]  (D row = j, D col = i)
  #pragma unroll
  for (int m = 0; m < 4; ++m) {
    #pragma unroll
    for (int n = 0; n < 4; ++n) {
      #pragma unroll
      for (int r = 0; r < 4; ++r) {
        int jloc = wj * 64 + m * 16 + lk * 4 + r;
        int iloc = wi * 64 + n * 16 + lr;
        tile[jloc * TPAD + iloc] =
            (unsigned short)f16key(__half_as_ushort(__float2half(acc[m][n][r])));
      }
    }
  }
  __syncthreads();

  // store 1: rows j of gk (coalesced 16B chunks)
  #pragma unroll
  for (int itr = 0; itr < 8; ++itr) {
    int idx = itr * 256 + tid;
    int row = idx >> 4, ch = idx & 15;
    u32x4 v = *(const u32x4*)&tile[row * TPAD + ch * 8];
    *(u32x4*)(gk + (size_t)(j0 + row) * HW + i0 + ch * 8) = v;
  }

  if (it != jt) {
    __syncthreads();  // WAR: store-1 reads done before refill
    // phase 2: transposed refill tile[iloc][jloc]; 4 keys pack -> one b64 write
    #pragma unroll
    for (int m = 0; m < 4; ++m) {
      #pragma unroll
      for (int n = 0; n < 4; ++n) {
        int il  = wi * 64 + n * 16 + lr;
        int jl0 = wj * 64 + m * 16 + lk * 4;
        unsigned long long pk =
            (unsigned long long)f16key(__half_as_ushort(__float2half(acc[m][n][0]))) |
            ((unsigned long long)f16key(__half_as_ushort(__float2half(acc[m][n][1]))) << 16) |
            ((unsigned long long)f16key(__half_as_ushort(__float2half(acc[m][n][2]))) << 32) |
            ((unsigned long long)f16key(__half_as_ushort(__float2half(acc[m][n][3]))) << 48);
        *(unsigned long long*)&tile[il * TPAD + jl0] = pk;
      }
    }
    __syncthreads();

    // store 2: mirror rows i of gk
    #pragma unroll
    for (int itr = 0; itr < 8; ++itr) {
      int idx = itr * 256 + tid;
      int row = idx >> 4, ch = idx & 15;
      u32x4 v = *(const u32x4*)&tile[row * TPAD + ch * 8];
      *(u32x4*)(gk + (size_t)(i0 + row) * HW + j0 + ch * 8) = v;
    }
  }
}

// ---------- kernel B: per-column top-115; 2 columns per wave (ILP) ----------
__launch_bounds__(256, 4)
__global__ void select_kernel(const unsigned short* __restrict__ gkeys,
                              float* __restrict__ out, int b_base) {
  __shared__ unsigned short cand[8][CAND];
  __shared__ unsigned int cnt[8];
  const int tid  = threadIdx.x;
  const int lane = tid & 63, wv = tid >> 6;
  const int bb = blockIdx.x >> 9;
  const int b  = b_base + bb;
  const int jA = ((blockIdx.x & 511) * 8) + wv * 2;
  const int jB = jA + 1;
  const u32x4* cpA = (const u32x4*)(gkeys + (size_t)bb * HW * HW + (size_t)jA * HW);
  const u32x4* cpB = (const u32x4*)(gkeys + (size_t)bb * HW * HW + (size_t)jB * HW);

  u32x4 qa0 = cpA[0 * 64 + lane], qa1 = cpA[1 * 64 + lane];
  u32x4 qa2 = cpA[2 * 64 + lane], qa3 = cpA[3 * 64 + lane];
  u32x4 qa4 = cpA[4 * 64 + lane], qa5 = cpA[5 * 64 + lane];
  u32x4 qa6 = cpA[6 * 64 + lane], qa7 = cpA[7 * 64 + lane];
  u32x4 qb0 = cpB[0 * 64 + lane], qb1 = cpB[1 * 64 + lane];
  u32x4 qb2 = cpB[2 * 64 + lane], qb3 = cpB[3 * 64 + lane];
  u32x4 qb4 = cpB[4 * 64 + lane], qb5 = cpB[5 * 64 + lane];
  u32x4 qb6 = cpB[6 * 64 + lane], qb7 = cpB[7 * 64 + lane];

  // two interleaved binary searches (independent dependency chains)
  unsigned int loA = 0, loB = 0;
  #pragma unroll 1
  for (int bit = 15; bit >= 0; --bit) {
    const unsigned int mA = loA | (1u << bit);
    const unsigned int mB = loB | (1u << bit);
    int cA = 0, cB = 0;
    cA += cmp2(qa0.x, mA) + cmp2(qa0.y, mA) + cmp2(qa0.z, mA) + cmp2(qa0.w, mA);
    cB += cmp2(qb0.x, mB) + cmp2(qb0.y, mB) + cmp2(qb0.z, mB) + cmp2(qb0.w, mB);
    cA += cmp2(qa1.x, mA) + cmp2(qa1.y, mA) + cmp2(qa1.z, mA) + cmp2(qa1.w, mA);
    cB += cmp2(qb1.x, mB) + cmp2(qb1.y, mB) + cmp2(qb1.z, mB) + cmp2(qb1.w, mB);
    cA += cmp2(qa2.x, mA) + cmp2(qa2.y, mA) + cmp2(qa2.z, mA) + cmp2(qa2.w, mA);
    cB += cmp2(qb2.x, mB) + cmp2(qb2.y, mB) + cmp2(qb2.z, mB) + cmp2(qb2.w, mB);
    cA += cmp2(qa3.x, mA) + cmp2(qa3.y, mA) + cmp2(qa3.z, mA) + cmp2(qa3.w, mA);
    cB += cmp2(qb3.x, mB) + cmp2(qb3.y, mB) + cmp2(qb3.z, mB) + cmp2(qb3.w, mB);
    cA += cmp2(qa4.x, mA) + cmp2(qa4.y, mA) + cmp2(qa4.z, mA) + cmp2(qa4.w, mA);
    cB += cmp2(qb4.x, mB) + cmp2(qb4.y, mB) + cmp2(qb4.z, mB) + cmp2(qb4.w, mB);
    cA += cmp2(qa5.x, mA) + cmp2(qa5.y, mA) + cmp2(qa5.z, mA) + cmp2(qa5.w, mA);
    cB += cmp2(qb5.x, mB) + cmp2(qb5.y, mB) + cmp2(qb5.z, mB) + cmp2(qb5.w, mB);
    cA += cmp2(qa6.x, mA) + cmp2(qa6.y, mA) + cmp2(qa6.z, mA) + cmp2(qa6.w, mA);
    cB += cmp2(qb6.x, mB) + cmp2(qb6.y, mB) + cmp2(qb6.z, mB) + cmp2(qb6.w, mB);
    cA += cmp2(qa7.x, mA) + cmp2(qa7.y, mA) + cmp2(qa7.z, mA) + cmp2(qa7.w, mA);
    cB += cmp2(qb7.x, mB) + cmp2(qb7.y, mB) + cmp2(qb7.z, mB) + cmp2(qb7.w, mB);
    cA += __shfl_xor(cA, 1);  cB += __shfl_xor(cB, 1);
    cA += __shfl_xor(cA, 2);  cB += __shfl_xor(cB, 2);
    cA += __shfl_xor(cA, 4);  cB += __shfl_xor(cB, 4);
    cA += __shfl_xor(cA, 8);  cB += __shfl_xor(cB, 8);
    cA += __shfl_xor(cA, 16); cB += __shfl_xor(cB, 16);
    cA += __shfl_xor(cA, 32); cB += __shfl_xor(cB, 32);
    if (cA >= K_TOP) loA = mA;
    if (cB >= K_TOP) loB = mB;
  }

  const int wa = wv * 2, wb = wv * 2 + 1;
  cand[wa][2 * lane] = (unsigned short)loA;
  cand[wa][2 * lane + 1] = (unsigned short)loA;
  cand[wb][2 * lane] = (unsigned short)loB;
  cand[wb][2 * lane + 1] = (unsigned short)loB;
  if (lane == 0) { cnt[wa] = 0; cnt[wb] = 0; }

  #define GATH(row, v, lo)                                       \
    { unsigned int _v = (v);                                     \
      if (_v > (lo)) {                                           \
        unsigned int _p = atomicAdd(&cnt[row], 1u);              \
        cand[row][_p] = (unsigned short)_v;                      \
      } }
  #define GATH4(row, q, lo)                                      \
    GATH(row, q.x & 0xffffu, lo) GATH(row, q.x >> 16, lo)        \
    GATH(row, q.y & 0xffffu, lo) GATH(row, q.y >> 16, lo)        \
    GATH(row, q.z & 0xffffu, lo) GATH(row, q.z >> 16, lo)        \
    GATH(row, q.w & 0xffffu, lo) GATH(row, q.w >> 16, lo)
  GATH4(wa, qa0, loA) GATH4(wa, qa1, loA) GATH4(wa, qa2, loA) GATH4(wa, qa3, loA)
  GATH4(wa, qa4, loA) GATH4(wa, qa5, loA) GATH4(wa, qa6, loA) GATH4(wa, qa7, loA)
  GATH4(wb, qb0, loB) GATH4(wb, qb1, loB) GATH4(wb, qb2, loB) GATH4(wb, qb3, loB)
  GATH4(wb, qb4, loB) GATH4(wb, qb5, loB) GATH4(wb, qb6, loB) GATH4(wb, qb7, loB)
  #undef GATH4
  #undef GATH

  asm volatile("" ::: "memory");  // scatter stores before read-back

  // rank-by-count, both columns interleaved (unique composite keys)
  unsigned int ka0 = cand[wa][2 * lane], ka1 = cand[wa][2 * lane + 1];
  unsigned int kb0 = cand[wb][2 * lane], kb1 = cand[wb][2 * lane + 1];
  unsigned int ca0 = (ka0 << 7) | (127u - (unsigned)(2 * lane));
  unsigned int ca1 = (ka1 << 7) | (127u - (unsigned)(2 * lane + 1));
  unsigned int cb0 = (kb0 << 7) | (127u - (unsigned)(2 * lane));
  unsigned int cb1 = (kb1 << 7) | (127u - (unsigned)(2 * lane + 1));
  int ra0 = 0, ra1 = 0, rb0 = 0, rb1 = 0;
  #pragma unroll 1
  for (int sl = 0; sl < 64; ++sl) {
    unsigned int da0 = __shfl(ca0, sl);
    unsigned int da1 = __shfl(ca1, sl);
    unsigned int db0 = __shfl(cb0, sl);
    unsigned int db1 = __shfl(cb1, sl);
    ra0 += (int)(da0 > ca0) + (int)(da1 > ca0);
    ra1 += (int)(da0 > ca1) + (int)(da1 > ca1);
    rb0 += (int)(db0 > cb0) + (int)(db1 > cb0);
    rb1 += (int)(db0 > cb1) + (int)(db1 > cb1);
  }
  if (ra0 < K_TOP)
    out[((size_t)b * K_TOP + ra0) * HW + jA] =
        __half2float(__ushort_as_half(key2f16(ka0))) * (1.0f / 256.0f);
  if (ra1 < K_TOP)
    out[((size_t)b * K_TOP + ra1) * HW + jA] =
        __half2float(__ushort_as_half(key2f16(ka1))) * (1.0f / 256.0f);
  if (rb0 < K_TOP)
    out[((size_t)b * K_TOP + rb0) * HW + jB] =
        __half2float(__ushort_as_half(key2f16(kb0))) * (1.0f / 256.0f);
  if (rb1 < K_TOP)
    out[((size_t)b * K_TOP + rb1) * HW + jB] =
        __half2float(__ushort_as_half(key2f16(kb1))) * (1.0f / 256.0f);
}

extern "C" void kernel_launch(void* const* d_in, const int* in_sizes, int n_in,
                              void* d_out, int out_size, void* d_ws, size_t ws_size,
                              hipStream_t stream) {
  (void)in_sizes; (void)n_in; (void)out_size;
  const float* x = (const float*)d_in[0];
  float* out = (float*)d_out;
  float* rn = (float*)d_ws;                                       // 64 KB
  unsigned short* xnT = (unsigned short*)((char*)d_ws + 65536);   // 8 MB bf16
  const size_t GK_OFF = 65536 + (size_t)8 * 1024 * 1024;
  const size_t ONE    = (size_t)HW * HW * 2;                      // 32 MB / batch
  const size_t NEED_1 = GK_OFF + ONE;
  const size_t NEED_4 = GK_OFF + 4 * ONE;                         // 136 MB

  norms_kernel<<<64, 256, 0, stream>>>(x, rn);
  transpose_kernel<<<1024, 256, 0, stream>>>(x, rn, xnT);

  if (ws_size >= NEED_4) {
    unsigned short* gkeys = (unsigned short*)((char*)d_ws + GK_OFF);
    gram_kernel<<<4 * NTRI, 256, 0, stream>>>(xnT, gkeys);
    select_kernel<<<4 * 512, 256, 0, stream>>>(gkeys, out, 0);
  } else if (ws_size >= NEED_1) {
    unsigned short* gkeys = (unsigned short*)((char*)d_ws + GK_OFF);
    for (int b = 0; b < 4; ++b) {
      gram_kernel<<<NTRI, 256, 0, stream>>>(xnT + (size_t)b * HW * CH, gkeys);
      select_kernel<<<512, 256, 0, stream>>>(gkeys, out, b);
    }
  }
}

// Round 9
// 193.045 us; speedup vs baseline: 1.9889x; 1.0184x over previous
//
#include <hip/hip_runtime.h>
#include <hip/hip_fp16.h>

#define CH 256
#define HW 4096
#define K_TOP 115
#define CAND 128
#define TPAD 152   // u16 row stride: 304B; 4-row offset = 16 mod 32 -> 2-way (free); rows 16B-aligned
#define NTRI 528   // 32*33/2 upper-triangle 128x128 tiles per batch
#define NTRI_H 264 // half-triangle per XCD

typedef __attribute__((ext_vector_type(8))) short short8;
typedef __attribute__((ext_vector_type(4))) float f32x4;
typedef __attribute__((ext_vector_type(4))) unsigned int u32x4;

__device__ __forceinline__ unsigned short f32_to_bf16(float f) {
  union { float f; unsigned int u; } v; v.f = f;
  unsigned int r = v.u + 0x7fffu + ((v.u >> 16) & 1u);
  return (unsigned short)(r >> 16);
}

__device__ __forceinline__ unsigned int f16key(unsigned short h) {
  return (h & 0x8000u) ? (unsigned int)((unsigned short)~h)
                       : (unsigned int)(h | 0x8000u);
}

__device__ __forceinline__ unsigned short key2f16(unsigned int k) {
  return (k & 0x8000u) ? (unsigned short)(k ^ 0x8000u)
                       : (unsigned short)(~k & 0xffffu);
}

// ---------- kernel 1a: rn[b][p] = 1 / max(||x[b,:,p]||, eps) ----------
__global__ void norms_kernel(const float* __restrict__ x, float* __restrict__ rn) {
  int b = blockIdx.x >> 4;
  int p = ((blockIdx.x & 15) << 8) + threadIdx.x;
  const float* xb = x + (size_t)b * CH * HW + p;
  float ss = 0.f;
  #pragma unroll 8
  for (int c = 0; c < CH; ++c) { float v = xb[(size_t)c * HW]; ss += v * v; }
  rn[b * HW + p] = 1.0f / fmaxf(sqrtf(ss), 1e-12f);
}

// ---------- kernel 1b: xnT[b][p][c] = bf16(x[b][c][p] * rn[b][p]) ----------
__global__ void transpose_kernel(const float* __restrict__ x, const float* __restrict__ rn,
                                 unsigned short* __restrict__ xnT) {
  __shared__ float tile[64][65];
  int blk = blockIdx.x;
  int b = blk >> 8;
  int rem = blk & 255;
  int c0 = (rem >> 6) << 6;
  int p0 = (rem & 63) << 6;
  for (int idx = threadIdx.x; idx < 64 * 64; idx += blockDim.x) {
    int c = idx >> 6, p = idx & 63;
    tile[c][p] = x[((size_t)b * CH + c0 + c) * HW + p0 + p];
  }
  __syncthreads();
  for (int idx = threadIdx.x; idx < 64 * 64; idx += blockDim.x) {
    int p = idx >> 6, c = idx & 63;
    xnT[((size_t)b * HW + p0 + p) * CH + c0 + c] =
        f32_to_bf16(tile[c][p] * rn[b * HW + p0 + p]);
  }
}

// ---------- kernel A: symmetric Gram -> u16 keys (row-major per batch) ----------
// nb==4: xcd = blk&7 owns batch xcd>>1 and half its triangle -> A-panel (2MB)
// stays resident in that XCD's 4MB L2. nb==1: plain per-batch grid (NTRI).
__launch_bounds__(256, 4)
__global__ void gram_kernel(const unsigned short* __restrict__ xnT,
                            unsigned short* __restrict__ gkeys, int nb) {
  __shared__ unsigned short tile[128 * TPAD];
  const int tid  = threadIdx.x;
  const int lane = tid & 63, wv = tid >> 6;
  const int wj = wv >> 1, wi = wv & 1;
  const int lr = lane & 15, lk = lane >> 4;

  int bb, t;
  if (nb == 4) {
    const int xcd = blockIdx.x & 7;
    bb = xcd >> 1;
    t  = ((xcd & 1) ? NTRI_H : 0) + (blockIdx.x >> 3);
  } else {
    bb = 0;
    t  = blockIdx.x;
  }
  // triangular decode: it = largest with it*(it+1)/2 <= t
  int it = (int)((sqrtf(8.0f * (float)t + 1.0f) - 1.0f) * 0.5f);
  while (((it + 1) * (it + 2)) / 2 <= t) ++it;
  while ((it * (it + 1)) / 2 > t) --it;
  const int jt = t - (it * (it + 1)) / 2;  // jt <= it
  const int j0 = jt * 128, i0 = it * 128;

  const short8* x8 = (const short8*)(xnT + (size_t)bb * HW * CH);
  unsigned short* gk = gkeys + (size_t)bb * HW * HW;

  f32x4 acc[4][4];
  #pragma unroll
  for (int m = 0; m < 4; ++m)
    #pragma unroll
    for (int n = 0; n < 4; ++n) acc[m][n] = (f32x4){0.f, 0.f, 0.f, 0.f};

  const int jbase = j0 + wj * 64 + lr;
  const int ibase = i0 + wi * 64 + lr;
  #pragma unroll
  for (int kk = 0; kk < 8; ++kk) {
    short8 af[4], bf[4];
    #pragma unroll
    for (int m = 0; m < 4; ++m)
      af[m] = x8[(size_t)(jbase + m * 16) * 32 + kk * 4 + lk];
    #pragma unroll
    for (int n = 0; n < 4; ++n)
      bf[n] = x8[(size_t)(ibase + n * 16) * 32 + kk * 4 + lk];
    #pragma unroll
    for (int m = 0; m < 4; ++m)
      #pragma unroll
      for (int n = 0; n < 4; ++n)
        acc[m][n] = __builtin_amdgcn_mfma_f32_16x16x32_bf16(af[m], bf[n],
                                                            acc[m][n], 0, 0, 0);
  }

  // phase 1: keys -> tile[jloc][iloc]  (D row = j, D col = i)
  #pragma unroll
  for (int m = 0; m < 4; ++m) {
    #pragma unroll
    for (int n = 0; n < 4; ++n) {
      #pragma unroll
      for (int r = 0; r < 4; ++r) {
        int jloc = wj * 64 + m * 16 + lk * 4 + r;
        int iloc = wi * 64 + n * 16 + lr;
        tile[jloc * TPAD + iloc] =
            (unsigned short)f16key(__half_as_ushort(__float2half(acc[m][n][r])));
      }
    }
  }
  __syncthreads();

  // store 1: rows j of gk (coalesced 16B chunks)
  #pragma unroll
  for (int itr = 0; itr < 8; ++itr) {
    int idx = itr * 256 + tid;
    int row = idx >> 4, ch = idx & 15;
    u32x4 v = *(const u32x4*)&tile[row * TPAD + ch * 8];
    *(u32x4*)(gk + (size_t)(j0 + row) * HW + i0 + ch * 8) = v;
  }

  if (it != jt) {
    __syncthreads();  // WAR: store-1 reads done before refill
    // phase 2: transposed refill tile[iloc][jloc]; 4 keys pack -> one b64 write
    #pragma unroll
    for (int m = 0; m < 4; ++m) {
      #pragma unroll
      for (int n = 0; n < 4; ++n) {
        int il  = wi * 64 + n * 16 + lr;
        int jl0 = wj * 64 + m * 16 + lk * 4;
        unsigned long long pk =
            (unsigned long long)f16key(__half_as_ushort(__float2half(acc[m][n][0]))) |
            ((unsigned long long)f16key(__half_as_ushort(__float2half(acc[m][n][1]))) << 16) |
            ((unsigned long long)f16key(__half_as_ushort(__float2half(acc[m][n][2]))) << 32) |
            ((unsigned long long)f16key(__half_as_ushort(__float2half(acc[m][n][3]))) << 48);
        *(unsigned long long*)&tile[il * TPAD + jl0] = pk;
      }
    }
    __syncthreads();

    // store 2: mirror rows i of gk
    #pragma unroll
    for (int itr = 0; itr < 8; ++itr) {
      int idx = itr * 256 + tid;
      int row = idx >> 4, ch = idx & 15;
      u32x4 v = *(const u32x4*)&tile[row * TPAD + ch * 8];
      *(u32x4*)(gk + (size_t)(i0 + row) * HW + j0 + ch * 8) = v;
    }
  }
}

// ---------- kernel B: per-column top-115, ballot-count binary search ----------
// One column per wave; 64 unpacked keys per lane. Count step =
// popcll(ballot(k>=m)): 1 v_cmp counts 64 keys; s_bcnt/s_add co-issue on the
// scalar pipe; binary-search state is wave-uniform (no shfl reduction at all).
__launch_bounds__(256, 4)
__global__ void select_kernel(const unsigned short* __restrict__ gkeys,
                              float* __restrict__ out, int b_base, int nb) {
  __shared__ unsigned short cand[4][CAND];
  __shared__ unsigned int cnt[4];
  const int tid  = threadIdx.x;
  const int lane = tid & 63, wv = tid >> 6;
  int bb, cg;
  if (nb == 4) {
    const int xcd = blockIdx.x & 7;
    bb = xcd >> 1;
    cg = ((xcd & 1) << 9) + (blockIdx.x >> 3);   // [0,1024)
  } else {
    bb = 0;
    cg = blockIdx.x;
  }
  const int b = b_base + bb;
  const int j = cg * 4 + wv;

  // load + unpack 64 keys/lane (order within lane is irrelevant for selection)
  unsigned int k[64];
  {
    const u32x4* cp4 = (const u32x4*)(gkeys + (size_t)bb * HW * HW + (size_t)j * HW);
    #pragma unroll
    for (int r = 0; r < 8; ++r) {
      u32x4 q = cp4[r * 64 + lane];
      k[8 * r + 0] = q.x & 0xffffu; k[8 * r + 1] = q.x >> 16;
      k[8 * r + 2] = q.y & 0xffffu; k[8 * r + 3] = q.y >> 16;
      k[8 * r + 4] = q.z & 0xffffu; k[8 * r + 5] = q.z >> 16;
      k[8 * r + 6] = q.w & 0xffffu; k[8 * r + 7] = q.w >> 16;
    }
  }

  // binary search: lo = max v with #{key >= v} >= 115 (exact threshold key)
  unsigned int lo = 0;
  #pragma unroll 1
  for (int bit = 15; bit >= 0; --bit) {
    const unsigned int m = lo | (1u << bit);
    int c = 0;
    #pragma unroll
    for (int r = 0; r < 64; ++r)
      c += (int)__popcll(__ballot(k[r] >= m));
    if (c >= K_TOP) lo = m;
  }

  // prefill candidates with threshold key (u16-typed accesses only — TBAA!)
  cand[wv][2 * lane]     = (unsigned short)lo;
  cand[wv][2 * lane + 1] = (unsigned short)lo;
  if (lane == 0) cnt[wv] = 0;

  // scatter strictly-greater keys (<=114 guaranteed) — wave-local LDS atomics
  #pragma unroll
  for (int r = 0; r < 64; ++r) {
    if (k[r] > lo) {
      unsigned int p = atomicAdd(&cnt[wv], 1u);
      cand[wv][p] = (unsigned short)k[r];
    }
  }

  asm volatile("" ::: "memory");  // scatter stores before read-back

  // rank-by-count over 128 candidates (unique composite keys -> unique ranks)
  unsigned int k0 = cand[wv][2 * lane];
  unsigned int k1 = cand[wv][2 * lane + 1];
  unsigned int c0 = (k0 << 7) | (127u - (unsigned)(2 * lane));
  unsigned int c1 = (k1 << 7) | (127u - (unsigned)(2 * lane + 1));
  int r0 = 0, r1 = 0;
  #pragma unroll 1
  for (int sl = 0; sl < 64; ++sl) {
    unsigned int d0 = __shfl(c0, sl);
    unsigned int d1 = __shfl(c1, sl);
    r0 += (int)(d0 > c0) + (int)(d1 > c0);
    r1 += (int)(d0 > c1) + (int)(d1 > c1);
  }
  if (r0 < K_TOP)
    out[((size_t)b * K_TOP + r0) * HW + j] =
        __half2float(__ushort_as_half(key2f16(k0))) * (1.0f / 256.0f);
  if (r1 < K_TOP)
    out[((size_t)b * K_TOP + r1) * HW + j] =
        __half2float(__ushort_as_half(key2f16(k1))) * (1.0f / 256.0f);
}

extern "C" void kernel_launch(void* const* d_in, const int* in_sizes, int n_in,
                              void* d_out, int out_size, void* d_ws, size_t ws_size,
                              hipStream_t stream) {
  (void)in_sizes; (void)n_in; (void)out_size;
  const float* x = (const float*)d_in[0];
  float* out = (float*)d_out;
  float* rn = (float*)d_ws;                                       // 64 KB
  unsigned short* xnT = (unsigned short*)((char*)d_ws + 65536);   // 8 MB bf16
  const size_t GK_OFF = 65536 + (size_t)8 * 1024 * 1024;
  const size_t ONE    = (size_t)HW * HW * 2;                      // 32 MB / batch
  const size_t NEED_1 = GK_OFF + ONE;
  const size_t NEED_4 = GK_OFF + 4 * ONE;                         // 136 MB

  norms_kernel<<<64, 256, 0, stream>>>(x, rn);
  transpose_kernel<<<1024, 256, 0, stream>>>(x, rn, xnT);

  if (ws_size >= NEED_4) {
    unsigned short* gkeys = (unsigned short*)((char*)d_ws + GK_OFF);
    gram_kernel<<<4 * NTRI, 256, 0, stream>>>(xnT, gkeys, 4);
    select_kernel<<<4096, 256, 0, stream>>>(gkeys, out, 0, 4);
  } else if (ws_size >= NEED_1) {
    unsigned short* gkeys = (unsigned short*)((char*)d_ws + GK_OFF);
    for (int b = 0; b < 4; ++b) {
      gram_kernel<<<NTRI, 256, 0, stream>>>(xnT + (size_t)b * HW * CH, gkeys, 1);
      select_kernel<<<1024, 256, 0, stream>>>(gkeys, out, b, 1);
    }
  }
}

// Round 10
// 192.516 us; speedup vs baseline: 1.9944x; 1.0027x over previous
//
#include <hip/hip_runtime.h>
#include <hip/hip_fp16.h>

#define CH 256
#define HW 4096
#define K_TOP 115
#define CAND 128
#define TPAD 152   // u16 row stride: 304B; 4-row offset = 16 mod 32 -> 2-way (free); rows 16B-aligned
#define NTRI 528   // 32*33/2 upper-triangle 128x128 tiles per batch
#define NTRI_H 264 // half-triangle per XCD

typedef __attribute__((ext_vector_type(8))) short short8;
typedef __attribute__((ext_vector_type(4))) float f32x4;
typedef __attribute__((ext_vector_type(4))) unsigned int u32x4;

__device__ __forceinline__ unsigned short f32_to_bf16(float f) {
  union { float f; unsigned int u; } v; v.f = f;
  unsigned int r = v.u + 0x7fffu + ((v.u >> 16) & 1u);
  return (unsigned short)(r >> 16);
}

__device__ __forceinline__ unsigned int f16key(unsigned short h) {
  return (h & 0x8000u) ? (unsigned int)((unsigned short)~h)
                       : (unsigned int)(h | 0x8000u);
}

__device__ __forceinline__ unsigned short key2f16(unsigned int k) {
  return (k & 0x8000u) ? (unsigned short)(k ^ 0x8000u)
                       : (unsigned short)(~k & 0xffffu);
}

// ---------- kernel 1a: rn[b][p] = 1 / max(||x[b,:,p]||, eps) ----------
__global__ void norms_kernel(const float* __restrict__ x, float* __restrict__ rn) {
  int b = blockIdx.x >> 4;
  int p = ((blockIdx.x & 15) << 8) + threadIdx.x;
  const float* xb = x + (size_t)b * CH * HW + p;
  float ss = 0.f;
  #pragma unroll 8
  for (int c = 0; c < CH; ++c) { float v = xb[(size_t)c * HW]; ss += v * v; }
  rn[b * HW + p] = 1.0f / fmaxf(sqrtf(ss), 1e-12f);
}

// ---------- kernel 1b: xnT[b][p][c] = bf16(x[b][c][p] * rn[b][p]) ----------
__global__ void transpose_kernel(const float* __restrict__ x, const float* __restrict__ rn,
                                 unsigned short* __restrict__ xnT) {
  __shared__ float tile[64][65];
  int blk = blockIdx.x;
  int b = blk >> 8;
  int rem = blk & 255;
  int c0 = (rem >> 6) << 6;
  int p0 = (rem & 63) << 6;
  for (int idx = threadIdx.x; idx < 64 * 64; idx += blockDim.x) {
    int c = idx >> 6, p = idx & 63;
    tile[c][p] = x[((size_t)b * CH + c0 + c) * HW + p0 + p];
  }
  __syncthreads();
  for (int idx = threadIdx.x; idx < 64 * 64; idx += blockDim.x) {
    int p = idx >> 6, c = idx & 63;
    xnT[((size_t)b * HW + p0 + p) * CH + c0 + c] =
        f32_to_bf16(tile[c][p] * rn[b * HW + p0 + p]);
  }
}

// ---------- kernel A: symmetric Gram -> u16 keys (row-major per batch) ----------
__launch_bounds__(256, 4)
__global__ void gram_kernel(const unsigned short* __restrict__ xnT,
                            unsigned short* __restrict__ gkeys, int nb) {
  __shared__ unsigned short tile[128 * TPAD];
  const int tid  = threadIdx.x;
  const int lane = tid & 63, wv = tid >> 6;
  const int wj = wv >> 1, wi = wv & 1;
  const int lr = lane & 15, lk = lane >> 4;

  int bb, t;
  if (nb == 4) {
    const int xcd = blockIdx.x & 7;
    bb = xcd >> 1;
    t  = ((xcd & 1) ? NTRI_H : 0) + (blockIdx.x >> 3);
  } else {
    bb = 0;
    t  = blockIdx.x;
  }
  int it = (int)((sqrtf(8.0f * (float)t + 1.0f) - 1.0f) * 0.5f);
  while (((it + 1) * (it + 2)) / 2 <= t) ++it;
  while ((it * (it + 1)) / 2 > t) --it;
  const int jt = t - (it * (it + 1)) / 2;  // jt <= it
  const int j0 = jt * 128, i0 = it * 128;

  const short8* x8 = (const short8*)(xnT + (size_t)bb * HW * CH);
  unsigned short* gk = gkeys + (size_t)bb * HW * HW;

  f32x4 acc[4][4];
  #pragma unroll
  for (int m = 0; m < 4; ++m)
    #pragma unroll
    for (int n = 0; n < 4; ++n) acc[m][n] = (f32x4){0.f, 0.f, 0.f, 0.f};

  const int jbase = j0 + wj * 64 + lr;
  const int ibase = i0 + wi * 64 + lr;
  #pragma unroll
  for (int kk = 0; kk < 8; ++kk) {
    short8 af[4], bf[4];
    #pragma unroll
    for (int m = 0; m < 4; ++m)
      af[m] = x8[(size_t)(jbase + m * 16) * 32 + kk * 4 + lk];
    #pragma unroll
    for (int n = 0; n < 4; ++n)
      bf[n] = x8[(size_t)(ibase + n * 16) * 32 + kk * 4 + lk];
    #pragma unroll
    for (int m = 0; m < 4; ++m)
      #pragma unroll
      for (int n = 0; n < 4; ++n)
        acc[m][n] = __builtin_amdgcn_mfma_f32_16x16x32_bf16(af[m], bf[n],
                                                            acc[m][n], 0, 0, 0);
  }

  // phase 1: keys -> tile[jloc][iloc]  (D row = j, D col = i)
  #pragma unroll
  for (int m = 0; m < 4; ++m) {
    #pragma unroll
    for (int n = 0; n < 4; ++n) {
      #pragma unroll
      for (int r = 0; r < 4; ++r) {
        int jloc = wj * 64 + m * 16 + lk * 4 + r;
        int iloc = wi * 64 + n * 16 + lr;
        tile[jloc * TPAD + iloc] =
            (unsigned short)f16key(__half_as_ushort(__float2half(acc[m][n][r])));
      }
    }
  }
  __syncthreads();

  // store 1: rows j of gk (coalesced 16B chunks)
  #pragma unroll
  for (int itr = 0; itr < 8; ++itr) {
    int idx = itr * 256 + tid;
    int row = idx >> 4, ch = idx & 15;
    u32x4 v = *(const u32x4*)&tile[row * TPAD + ch * 8];
    *(u32x4*)(gk + (size_t)(j0 + row) * HW + i0 + ch * 8) = v;
  }

  if (it != jt) {
    __syncthreads();  // WAR: store-1 reads done before refill
    #pragma unroll
    for (int m = 0; m < 4; ++m) {
      #pragma unroll
      for (int n = 0; n < 4; ++n) {
        int il  = wi * 64 + n * 16 + lr;
        int jl0 = wj * 64 + m * 16 + lk * 4;
        unsigned long long pk =
            (unsigned long long)f16key(__half_as_ushort(__float2half(acc[m][n][0]))) |
            ((unsigned long long)f16key(__half_as_ushort(__float2half(acc[m][n][1]))) << 16) |
            ((unsigned long long)f16key(__half_as_ushort(__float2half(acc[m][n][2]))) << 32) |
            ((unsigned long long)f16key(__half_as_ushort(__float2half(acc[m][n][3]))) << 48);
        *(unsigned long long*)&tile[il * TPAD + jl0] = pk;
      }
    }
    __syncthreads();

    // store 2: mirror rows i of gk
    #pragma unroll
    for (int itr = 0; itr < 8; ++itr) {
      int idx = itr * 256 + tid;
      int row = idx >> 4, ch = idx & 15;
      u32x4 v = *(const u32x4*)&tile[row * TPAD + ch * 8];
      *(u32x4*)(gk + (size_t)(i0 + row) * HW + j0 + ch * 8) = v;
    }
  }
}

// ---------- kernel B: per-column top-115, ballot-count with NAMED key regs ----------
// One column per wave; 64 keys per lane in 64 individually-named VGPRs (R9's
// k[64] array spilled to scratch -> VGPR_Count 20; named scalars force
// register residency). Count = popcll(ballot(K>=m)): 1 v_cmp per key counts
// all 64 lanes; bcnt/add co-issue on the scalar pipe; no shfl reduction.
#define APPLY64(M) \
  M(0) M(1) M(2) M(3) M(4) M(5) M(6) M(7) \
  M(8) M(9) M(10) M(11) M(12) M(13) M(14) M(15) \
  M(16) M(17) M(18) M(19) M(20) M(21) M(22) M(23) \
  M(24) M(25) M(26) M(27) M(28) M(29) M(30) M(31) \
  M(32) M(33) M(34) M(35) M(36) M(37) M(38) M(39) \
  M(40) M(41) M(42) M(43) M(44) M(45) M(46) M(47) \
  M(48) M(49) M(50) M(51) M(52) M(53) M(54) M(55) \
  M(56) M(57) M(58) M(59) M(60) M(61) M(62) M(63)

__launch_bounds__(256, 4)
__global__ void select_kernel(const unsigned short* __restrict__ gkeys,
                              float* __restrict__ out, int b_base, int nb) {
  __shared__ unsigned short cand[4][CAND];
  __shared__ unsigned int cnt[4];
  const int tid  = threadIdx.x;
  const int lane = tid & 63, wv = tid >> 6;
  int bb, cg;
  if (nb == 4) {
    const int xcd = blockIdx.x & 7;
    bb = xcd >> 1;
    cg = ((xcd & 1) << 9) + (blockIdx.x >> 3);   // [0,1024)
  } else {
    bb = 0;
    cg = blockIdx.x;
  }
  const int b = b_base + bb;
  const int j = cg * 4 + wv;

  // 64 named key registers
  #define KDECL(i) unsigned int K##i;
  APPLY64(KDECL)
  #undef KDECL

  {
    const u32x4* cp4 = (const u32x4*)(gkeys + (size_t)bb * HW * HW + (size_t)j * HW);
    u32x4 q0 = cp4[0 * 64 + lane], q1 = cp4[1 * 64 + lane];
    u32x4 q2 = cp4[2 * 64 + lane], q3 = cp4[3 * 64 + lane];
    u32x4 q4 = cp4[4 * 64 + lane], q5 = cp4[5 * 64 + lane];
    u32x4 q6 = cp4[6 * 64 + lane], q7 = cp4[7 * 64 + lane];
    K0  = q0.x & 0xffffu; K1  = q0.x >> 16; K2  = q0.y & 0xffffu; K3  = q0.y >> 16;
    K4  = q0.z & 0xffffu; K5  = q0.z >> 16; K6  = q0.w & 0xffffu; K7  = q0.w >> 16;
    K8  = q1.x & 0xffffu; K9  = q1.x >> 16; K10 = q1.y & 0xffffu; K11 = q1.y >> 16;
    K12 = q1.z & 0xffffu; K13 = q1.z >> 16; K14 = q1.w & 0xffffu; K15 = q1.w >> 16;
    K16 = q2.x & 0xffffu; K17 = q2.x >> 16; K18 = q2.y & 0xffffu; K19 = q2.y >> 16;
    K20 = q2.z & 0xffffu; K21 = q2.z >> 16; K22 = q2.w & 0xffffu; K23 = q2.w >> 16;
    K24 = q3.x & 0xffffu; K25 = q3.x >> 16; K26 = q3.y & 0xffffu; K27 = q3.y >> 16;
    K28 = q3.z & 0xffffu; K29 = q3.z >> 16; K30 = q3.w & 0xffffu; K31 = q3.w >> 16;
    K32 = q4.x & 0xffffu; K33 = q4.x >> 16; K34 = q4.y & 0xffffu; K35 = q4.y >> 16;
    K36 = q4.z & 0xffffu; K37 = q4.z >> 16; K38 = q4.w & 0xffffu; K39 = q4.w >> 16;
    K40 = q5.x & 0xffffu; K41 = q5.x >> 16; K42 = q5.y & 0xffffu; K43 = q5.y >> 16;
    K44 = q5.z & 0xffffu; K45 = q5.z >> 16; K46 = q5.w & 0xffffu; K47 = q5.w >> 16;
    K48 = q6.x & 0xffffu; K49 = q6.x >> 16; K50 = q6.y & 0xffffu; K51 = q6.y >> 16;
    K52 = q6.z & 0xffffu; K53 = q6.z >> 16; K54 = q6.w & 0xffffu; K55 = q6.w >> 16;
    K56 = q7.x & 0xffffu; K57 = q7.x >> 16; K58 = q7.y & 0xffffu; K59 = q7.y >> 16;
    K60 = q7.z & 0xffffu; K61 = q7.z >> 16; K62 = q7.w & 0xffffu; K63 = q7.w >> 16;
  }

  // binary search: lo = max v with #{key >= v} >= 115 (exact threshold key)
  unsigned int lo = 0;
  #pragma unroll 1
  for (int bit = 15; bit >= 0; --bit) {
    const unsigned int m = lo | (1u << bit);
    int c = 0;
    #define CNT1(i) c += (int)__popcll(__ballot(K##i >= m));
    APPLY64(CNT1)
    #undef CNT1
    if (c >= K_TOP) lo = m;
  }

  // prefill candidates with threshold key (u16-typed accesses only — TBAA!)
  cand[wv][2 * lane]     = (unsigned short)lo;
  cand[wv][2 * lane + 1] = (unsigned short)lo;
  if (lane == 0) cnt[wv] = 0;

  // scatter strictly-greater keys (<=114 guaranteed) — wave-local LDS atomics
  #define GATH1(i)                                               \
    if (K##i > lo) {                                             \
      unsigned int p_ = atomicAdd(&cnt[wv], 1u);                 \
      cand[wv][p_] = (unsigned short)K##i;                       \
    }
  APPLY64(GATH1)
  #undef GATH1

  asm volatile("" ::: "memory");  // scatter stores before read-back

  // rank-by-count over 128 candidates (unique composite keys -> unique ranks)
  unsigned int k0 = cand[wv][2 * lane];
  unsigned int k1 = cand[wv][2 * lane + 1];
  unsigned int c0 = (k0 << 7) | (127u - (unsigned)(2 * lane));
  unsigned int c1 = (k1 << 7) | (127u - (unsigned)(2 * lane + 1));
  int r0 = 0, r1 = 0;
  #pragma unroll 1
  for (int sl = 0; sl < 64; ++sl) {
    unsigned int d0 = __shfl(c0, sl);
    unsigned int d1 = __shfl(c1, sl);
    r0 += (int)(d0 > c0) + (int)(d1 > c0);
    r1 += (int)(d0 > c1) + (int)(d1 > c1);
  }
  if (r0 < K_TOP)
    out[((size_t)b * K_TOP + r0) * HW + j] =
        __half2float(__ushort_as_half(key2f16(k0))) * (1.0f / 256.0f);
  if (r1 < K_TOP)
    out[((size_t)b * K_TOP + r1) * HW + j] =
        __half2float(__ushort_as_half(key2f16(k1))) * (1.0f / 256.0f);
}

extern "C" void kernel_launch(void* const* d_in, const int* in_sizes, int n_in,
                              void* d_out, int out_size, void* d_ws, size_t ws_size,
                              hipStream_t stream) {
  (void)in_sizes; (void)n_in; (void)out_size;
  const float* x = (const float*)d_in[0];
  float* out = (float*)d_out;
  float* rn = (float*)d_ws;                                       // 64 KB
  unsigned short* xnT = (unsigned short*)((char*)d_ws + 65536);   // 8 MB bf16
  const size_t GK_OFF = 65536 + (size_t)8 * 1024 * 1024;
  const size_t ONE    = (size_t)HW * HW * 2;                      // 32 MB / batch
  const size_t NEED_1 = GK_OFF + ONE;
  const size_t NEED_4 = GK_OFF + 4 * ONE;                         // 136 MB

  norms_kernel<<<64, 256, 0, stream>>>(x, rn);
  transpose_kernel<<<1024, 256, 0, stream>>>(x, rn, xnT);

  if (ws_size >= NEED_4) {
    unsigned short* gkeys = (unsigned short*)((char*)d_ws + GK_OFF);
    gram_kernel<<<4 * NTRI, 256, 0, stream>>>(xnT, gkeys, 4);
    select_kernel<<<4096, 256, 0, stream>>>(gkeys, out, 0, 4);
  } else if (ws_size >= NEED_1) {
    unsigned short* gkeys = (unsigned short*)((char*)d_ws + GK_OFF);
    for (int b = 0; b < 4; ++b) {
      gram_kernel<<<NTRI, 256, 0, stream>>>(xnT + (size_t)b * HW * CH, gkeys, 1);
      select_kernel<<<1024, 256, 0, stream>>>(gkeys, out, b, 1);
    }
  }
}

// Round 11
// 178.554 us; speedup vs baseline: 2.1503x; 1.0782x over previous
//
#include <hip/hip_runtime.h>
#include <hip/hip_fp16.h>

#define CH 256
#define HW 4096
#define K_TOP 115
#define CAND 128
#define TPAD 152   // u16 row stride: 304B; 4-row offset = 16 mod 32 -> 2-way (free); rows 16B-aligned
#define NTRI 528   // 32*33/2 upper-triangle 128x128 tiles per batch
#define NTRI_H 264 // half-triangle per XCD

typedef __attribute__((ext_vector_type(8))) short short8;
typedef __attribute__((ext_vector_type(4))) float f32x4;
typedef __attribute__((ext_vector_type(4))) unsigned int u32x4;

__device__ __forceinline__ unsigned short f32_to_bf16(float f) {
  union { float f; unsigned int u; } v; v.f = f;
  unsigned int r = v.u + 0x7fffu + ((v.u >> 16) & 1u);
  return (unsigned short)(r >> 16);
}

__device__ __forceinline__ unsigned int f16key(unsigned short h) {
  return (h & 0x8000u) ? (unsigned int)((unsigned short)~h)
                       : (unsigned int)(h | 0x8000u);
}

__device__ __forceinline__ unsigned short key2f16(unsigned int k) {
  return (k & 0x8000u) ? (unsigned short)(k ^ 0x8000u)
                       : (unsigned short)(~k & 0xffffu);
}

// ---------- kernel 1a: rn[b][p] = 1 / max(||x[b,:,p]||, eps) ----------
__global__ void norms_kernel(const float* __restrict__ x, float* __restrict__ rn) {
  int b = blockIdx.x >> 4;
  int p = ((blockIdx.x & 15) << 8) + threadIdx.x;
  const float* xb = x + (size_t)b * CH * HW + p;
  float ss = 0.f;
  #pragma unroll 8
  for (int c = 0; c < CH; ++c) { float v = xb[(size_t)c * HW]; ss += v * v; }
  rn[b * HW + p] = 1.0f / fmaxf(sqrtf(ss), 1e-12f);
}

// ---------- kernel 1b: xnT[b][p][c] = bf16(x[b][c][p] * rn[b][p]) ----------
__global__ void transpose_kernel(const float* __restrict__ x, const float* __restrict__ rn,
                                 unsigned short* __restrict__ xnT) {
  __shared__ float tile[64][65];
  int blk = blockIdx.x;
  int b = blk >> 8;
  int rem = blk & 255;
  int c0 = (rem >> 6) << 6;
  int p0 = (rem & 63) << 6;
  for (int idx = threadIdx.x; idx < 64 * 64; idx += blockDim.x) {
    int c = idx >> 6, p = idx & 63;
    tile[c][p] = x[((size_t)b * CH + c0 + c) * HW + p0 + p];
  }
  __syncthreads();
  for (int idx = threadIdx.x; idx < 64 * 64; idx += blockDim.x) {
    int p = idx >> 6, c = idx & 63;
    xnT[((size_t)b * HW + p0 + p) * CH + c0 + c] =
        f32_to_bf16(tile[c][p] * rn[b * HW + p0 + p]);
  }
}

// ---------- kernel A: symmetric Gram -> u16 keys (row-major per batch) ----------
__launch_bounds__(256, 4)
__global__ void gram_kernel(const unsigned short* __restrict__ xnT,
                            unsigned short* __restrict__ gkeys, int nb) {
  __shared__ unsigned short tile[128 * TPAD];
  const int tid  = threadIdx.x;
  const int lane = tid & 63, wv = tid >> 6;
  const int wj = wv >> 1, wi = wv & 1;
  const int lr = lane & 15, lk = lane >> 4;

  int bb, t;
  if (nb == 4) {
    const int xcd = blockIdx.x & 7;
    bb = xcd >> 1;
    t  = ((xcd & 1) ? NTRI_H : 0) + (blockIdx.x >> 3);
  } else {
    bb = 0;
    t  = blockIdx.x;
  }
  int it = (int)((sqrtf(8.0f * (float)t + 1.0f) - 1.0f) * 0.5f);
  while (((it + 1) * (it + 2)) / 2 <= t) ++it;
  while ((it * (it + 1)) / 2 > t) --it;
  const int jt = t - (it * (it + 1)) / 2;  // jt <= it
  const int j0 = jt * 128, i0 = it * 128;

  const short8* x8 = (const short8*)(xnT + (size_t)bb * HW * CH);
  unsigned short* gk = gkeys + (size_t)bb * HW * HW;

  f32x4 acc[4][4];
  #pragma unroll
  for (int m = 0; m < 4; ++m)
    #pragma unroll
    for (int n = 0; n < 4; ++n) acc[m][n] = (f32x4){0.f, 0.f, 0.f, 0.f};

  const int jbase = j0 + wj * 64 + lr;
  const int ibase = i0 + wi * 64 + lr;
  #pragma unroll
  for (int kk = 0; kk < 8; ++kk) {
    short8 af[4], bf[4];
    #pragma unroll
    for (int m = 0; m < 4; ++m)
      af[m] = x8[(size_t)(jbase + m * 16) * 32 + kk * 4 + lk];
    #pragma unroll
    for (int n = 0; n < 4; ++n)
      bf[n] = x8[(size_t)(ibase + n * 16) * 32 + kk * 4 + lk];
    #pragma unroll
    for (int m = 0; m < 4; ++m)
      #pragma unroll
      for (int n = 0; n < 4; ++n)
        acc[m][n] = __builtin_amdgcn_mfma_f32_16x16x32_bf16(af[m], bf[n],
                                                            acc[m][n], 0, 0, 0);
  }

  // phase 1: keys -> tile[jloc][iloc]  (D row = j, D col = i)
  #pragma unroll
  for (int m = 0; m < 4; ++m) {
    #pragma unroll
    for (int n = 0; n < 4; ++n) {
      #pragma unroll
      for (int r = 0; r < 4; ++r) {
        int jloc = wj * 64 + m * 16 + lk * 4 + r;
        int iloc = wi * 64 + n * 16 + lr;
        tile[jloc * TPAD + iloc] =
            (unsigned short)f16key(__half_as_ushort(__float2half(acc[m][n][r])));
      }
    }
  }
  __syncthreads();

  // store 1: rows j of gk (coalesced 16B chunks)
  #pragma unroll
  for (int itr = 0; itr < 8; ++itr) {
    int idx = itr * 256 + tid;
    int row = idx >> 4, ch = idx & 15;
    u32x4 v = *(const u32x4*)&tile[row * TPAD + ch * 8];
    *(u32x4*)(gk + (size_t)(j0 + row) * HW + i0 + ch * 8) = v;
  }

  if (it != jt) {
    __syncthreads();  // WAR: store-1 reads done before refill
    #pragma unroll
    for (int m = 0; m < 4; ++m) {
      #pragma unroll
      for (int n = 0; n < 4; ++n) {
        int il  = wi * 64 + n * 16 + lr;
        int jl0 = wj * 64 + m * 16 + lk * 4;
        unsigned long long pk =
            (unsigned long long)f16key(__half_as_ushort(__float2half(acc[m][n][0]))) |
            ((unsigned long long)f16key(__half_as_ushort(__float2half(acc[m][n][1]))) << 16) |
            ((unsigned long long)f16key(__half_as_ushort(__float2half(acc[m][n][2]))) << 32) |
            ((unsigned long long)f16key(__half_as_ushort(__float2half(acc[m][n][3]))) << 48);
        *(unsigned long long*)&tile[il * TPAD + jl0] = pk;
      }
    }
    __syncthreads();

    // store 2: mirror rows i of gk
    #pragma unroll
    for (int itr = 0; itr < 8; ++itr) {
      int idx = itr * 256 + tid;
      int row = idx >> 4, ch = idx & 15;
      u32x4 v = *(const u32x4*)&tile[row * TPAD + ch * 8];
      *(u32x4*)(gk + (size_t)(i0 + row) * HW + j0 + ch * 8) = v;
    }
  }
}

// ---------- kernel B: per-column top-115, SWAR packed counting ----------
// Keys stay PACKED in 8 u32x4 (32 VGPRs — the only layout hipcc keeps
// register-resident; R9/R10's unpacked 64 keys spilled, VGPR_Count=20).
// Corr in [-1.008,1.008] => keys in [0x43F0,0xBC10] => 15-bit after -0x4000.
// P = (q-0x40004000)|0x80008000; (P - m*0x10001) & 0x80008000 has bit15/31
// set iff each half >= m — borrow can't cross (halves of P >= 0x8000,
// m <= 0x7fff). Count = 1 sub + 1 and + 1 bcnt per packed reg per round.
__launch_bounds__(256, 4)
__global__ void select_kernel(const unsigned short* __restrict__ gkeys,
                              float* __restrict__ out, int b_base, int nb) {
  __shared__ unsigned short cand[4][CAND];
  __shared__ unsigned int cnt[4];
  const int tid  = threadIdx.x;
  const int lane = tid & 63, wv = tid >> 6;
  int bb, cg;
  if (nb == 4) {
    const int xcd = blockIdx.x & 7;
    bb = xcd >> 1;
    cg = ((xcd & 1) << 9) + (blockIdx.x >> 3);   // [0,1024)
  } else {
    bb = 0;
    cg = blockIdx.x;
  }
  const int b = b_base + bb;
  const int j = cg * 4 + wv;

  const u32x4* cp4 = (const u32x4*)(gkeys + (size_t)bb * HW * HW + (size_t)j * HW);
  u32x4 q0 = cp4[0 * 64 + lane], q1 = cp4[1 * 64 + lane];
  u32x4 q2 = cp4[2 * 64 + lane], q3 = cp4[3 * 64 + lane];
  u32x4 q4 = cp4[4 * 64 + lane], q5 = cp4[5 * 64 + lane];
  u32x4 q6 = cp4[6 * 64 + lane], q7 = cp4[7 * 64 + lane];

  // one-time SWAR transform (keys remain recoverable: half & 0x7fff)
  q0 = (q0 - 0x40004000u) | 0x80008000u;
  q1 = (q1 - 0x40004000u) | 0x80008000u;
  q2 = (q2 - 0x40004000u) | 0x80008000u;
  q3 = (q3 - 0x40004000u) | 0x80008000u;
  q4 = (q4 - 0x40004000u) | 0x80008000u;
  q5 = (q5 - 0x40004000u) | 0x80008000u;
  q6 = (q6 - 0x40004000u) | 0x80008000u;
  q7 = (q7 - 0x40004000u) | 0x80008000u;

  // binary search in 15-bit space: lo = max v with #{k15 >= v} >= 115
  unsigned int lo = 0;
  #pragma unroll 1
  for (int bit = 14; bit >= 0; --bit) {
    const unsigned int m  = lo | (1u << bit);
    const unsigned int mm = m * 0x10001u;
    int c = 0;
    #define CNTV(Q) \
      c += (int)__builtin_popcount((Q.x - mm) & 0x80008000u); \
      c += (int)__builtin_popcount((Q.y - mm) & 0x80008000u); \
      c += (int)__builtin_popcount((Q.z - mm) & 0x80008000u); \
      c += (int)__builtin_popcount((Q.w - mm) & 0x80008000u);
    CNTV(q0) CNTV(q1) CNTV(q2) CNTV(q3)
    CNTV(q4) CNTV(q5) CNTV(q6) CNTV(q7)
    #undef CNTV
    c += __shfl_xor(c, 1);
    c += __shfl_xor(c, 2);
    c += __shfl_xor(c, 4);
    c += __shfl_xor(c, 8);
    c += __shfl_xor(c, 16);
    c += __shfl_xor(c, 32);
    if (c >= K_TOP) lo = m;
  }
  // lo is an actual key15 whenever padding occurs (count(lo)>count(lo+1)).

  // prefill candidates with threshold (15-bit values; u16-typed — TBAA!)
  cand[wv][2 * lane]     = (unsigned short)lo;
  cand[wv][2 * lane + 1] = (unsigned short)lo;
  if (lane == 0) cnt[wv] = 0;

  // scatter strictly-greater 15-bit keys (<=114 guaranteed)
  #define GATH(v)                                                \
    { unsigned int _v = (v);                                     \
      if (_v > lo) {                                             \
        unsigned int _p = atomicAdd(&cnt[wv], 1u);               \
        cand[wv][_p] = (unsigned short)_v;                       \
      } }
  #define GATH4(Q)                                               \
    GATH(Q.x & 0x7fffu) GATH((Q.x >> 16) & 0x7fffu)              \
    GATH(Q.y & 0x7fffu) GATH((Q.y >> 16) & 0x7fffu)              \
    GATH(Q.z & 0x7fffu) GATH((Q.z >> 16) & 0x7fffu)              \
    GATH(Q.w & 0x7fffu) GATH((Q.w >> 16) & 0x7fffu)
  GATH4(q0) GATH4(q1) GATH4(q2) GATH4(q3)
  GATH4(q4) GATH4(q5) GATH4(q6) GATH4(q7)
  #undef GATH4
  #undef GATH

  asm volatile("" ::: "memory");  // scatter stores before read-back

  // rank-by-count over 128 candidates (unique composite keys -> unique ranks)
  unsigned int k0 = cand[wv][2 * lane];
  unsigned int k1 = cand[wv][2 * lane + 1];
  unsigned int c0 = (k0 << 7) | (127u - (unsigned)(2 * lane));
  unsigned int c1 = (k1 << 7) | (127u - (unsigned)(2 * lane + 1));
  int r0 = 0, r1 = 0;
  #pragma unroll 1
  for (int sl = 0; sl < 64; ++sl) {
    unsigned int d0 = __shfl(c0, sl);
    unsigned int d1 = __shfl(c1, sl);
    r0 += (int)(d0 > c0) + (int)(d1 > c0);
    r1 += (int)(d0 > c1) + (int)(d1 > c1);
  }
  if (r0 < K_TOP)
    out[((size_t)b * K_TOP + r0) * HW + j] =
        __half2float(__ushort_as_half(key2f16(k0 + 0x4000u))) * (1.0f / 256.0f);
  if (r1 < K_TOP)
    out[((size_t)b * K_TOP + r1) * HW + j] =
        __half2float(__ushort_as_half(key2f16(k1 + 0x4000u))) * (1.0f / 256.0f);
}

extern "C" void kernel_launch(void* const* d_in, const int* in_sizes, int n_in,
                              void* d_out, int out_size, void* d_ws, size_t ws_size,
                              hipStream_t stream) {
  (void)in_sizes; (void)n_in; (void)out_size;
  const float* x = (const float*)d_in[0];
  float* out = (float*)d_out;
  float* rn = (float*)d_ws;                                       // 64 KB
  unsigned short* xnT = (unsigned short*)((char*)d_ws + 65536);   // 8 MB bf16
  const size_t GK_OFF = 65536 + (size_t)8 * 1024 * 1024;
  const size_t ONE    = (size_t)HW * HW * 2;                      // 32 MB / batch
  const size_t NEED_1 = GK_OFF + ONE;
  const size_t NEED_4 = GK_OFF + 4 * ONE;                         // 136 MB

  norms_kernel<<<64, 256, 0, stream>>>(x, rn);
  transpose_kernel<<<1024, 256, 0, stream>>>(x, rn, xnT);

  if (ws_size >= NEED_4) {
    unsigned short* gkeys = (unsigned short*)((char*)d_ws + GK_OFF);
    gram_kernel<<<4 * NTRI, 256, 0, stream>>>(xnT, gkeys, 4);
    select_kernel<<<4096, 256, 0, stream>>>(gkeys, out, 0, 4);
  } else if (ws_size >= NEED_1) {
    unsigned short* gkeys = (unsigned short*)((char*)d_ws + GK_OFF);
    for (int b = 0; b < 4; ++b) {
      gram_kernel<<<NTRI, 256, 0, stream>>>(xnT + (size_t)b * HW * CH, gkeys, 1);
      select_kernel<<<1024, 256, 0, stream>>>(gkeys, out, b, 1);
    }
  }
}